// Round 13
// baseline (272.568 us; speedup 1.0000x reference)
//
#include <hip/hip_runtime.h>

// ---------------------------------------------------------------------------
// MLA (LoraQKV) pipeline for MI355X, bf16 MFMA everywhere.
//   1) cvt_all; 2) gemm C1 = hs@W1^T (f32); 3) rmsnorm_rope;
//   4) grouped gemm Qfb+KVfb (bf16 out, one launch); 5) kv_post (V^T);
//   6) flash_attn (Q-RoPE fused, K from KVfb+kr, 2-way key-split) + combine;
//   7) gemm out = Ao@o_w^T (f32).
// R13: flash __launch_bounds__(256,5) -> 5 blocks/CU (LDS=32KB exactly fits);
//     gemm2a+2b merged into one grouped 2048-block launch (tail overlap).
//     All else identical to R12 (passing, absmax 9.8e-3).
// ---------------------------------------------------------------------------

typedef __attribute__((ext_vector_type(8))) __bf16 bf16x8;
typedef __attribute__((ext_vector_type(4))) float f32x4;
typedef __attribute__((ext_vector_type(4))) unsigned u32x4;

__device__ __forceinline__ unsigned short f2bf(float f) {
  unsigned int x = __builtin_bit_cast(unsigned int, f);
  x += 0x7fffu + ((x >> 16) & 1u);
  return (unsigned short)(x >> 16);
}
__device__ __forceinline__ float bf2f(unsigned short u) {
  unsigned int x = ((unsigned int)u) << 16;
  return __builtin_bit_cast(float, x);
}
__device__ __forceinline__ void gload_lds16(const void* g, void* l) {
  __builtin_amdgcn_global_load_lds(
      (const __attribute__((address_space(1))) void*)g,
      (__attribute__((address_space(3))) void*)l, 16, 0, 0);
}
__device__ __forceinline__ void cstore(float* C, size_t i, float v) { C[i] = v; }
__device__ __forceinline__ void cstore(unsigned short* C, size_t i, float v) { C[i] = f2bf(v); }

// ---------------- segmented convert (all f32->bf16 converts in one launch) --
struct CvtSegs {
  const float* src[6];
  unsigned short* dst[6];
  unsigned int n_src[6];
  unsigned int n_tot[6];
  unsigned int blk0[7];
};

__global__ __launch_bounds__(256) void cvt_all(CvtSegs sg) {
  int b = blockIdx.x;
  int seg = 0;
#pragma unroll
  for (int k = 0; k < 5; ++k)
    if (b >= (int)sg.blk0[k + 1]) seg = k + 1;
  size_t i = ((size_t)(b - sg.blk0[seg]) * 256 + threadIdx.x) * 4;
  if (i >= sg.n_tot[seg]) return;
  unsigned short o0 = 0, o1 = 0, o2 = 0, o3 = 0;
  if (i < sg.n_src[seg]) {
    float4 v = *reinterpret_cast<const float4*>(sg.src[seg] + i);
    o0 = f2bf(v.x); o1 = f2bf(v.y); o2 = f2bf(v.z); o3 = f2bf(v.w);
  }
  *reinterpret_cast<ushort4*>(sg.dst[seg] + i) = make_ushort4(o0, o1, o2, o3);
}

// ---------------- GEMM core (shared by single and grouped kernels) ----------
// 128x64 tile, BK=64, 512 threads (8 waves 4x2, wave tile 32x32), dbuf LDS,
// 2-phase; T2 swizzle via pre-swizzled gload source.
template <typename OutT>
__device__ __forceinline__ void gemm_body(const unsigned short* __restrict__ A,
                                          const unsigned short* __restrict__ B,
                                          OutT* __restrict__ C,
                                          int N, int K, int bm, int bn,
                                          unsigned short* lA0, unsigned short* lA1,
                                          unsigned short* lB0, unsigned short* lB1) {
  const int tid = threadIdx.x, lane = tid & 63, wv = tid >> 6;
  const int wr = wv >> 1, wc = wv & 1;             // 4x2 wave grid

  f32x4 acc[2][2] = {};

  const int ar0 = tid >> 3;
  const int acol = (((tid & 7) ^ ((tid >> 3) & 7))) * 8;   // T2 pre-swizzled src
  const int swz = lane & 7;

  auto stage = [&](unsigned short* la, unsigned short* lb, int k0) {
#pragma unroll
    for (int i = 0; i < 2; ++i)
      gload_lds16(A + (size_t)(bm + i * 64 + ar0) * K + k0 + acol,
                  &la[(i * 512 + wv * 64) * 8]);
    gload_lds16(B + (size_t)(bn + ar0) * K + k0 + acol, &lb[(wv * 64) * 8]);
  };

  auto compute = [&](const unsigned short* la, const unsigned short* lb) {
#pragma unroll
    for (int ks = 0; ks < 2; ++ks) {
      const int ch = ((ks * 4 + (lane >> 4)) ^ swz) * 8;
      bf16x8 af[2], bfr[2];
#pragma unroll
      for (int m = 0; m < 2; ++m)
        af[m] = *reinterpret_cast<const bf16x8*>(
            &la[(wr * 32 + m * 16 + (lane & 15)) * 64 + ch]);
#pragma unroll
      for (int n = 0; n < 2; ++n)
        bfr[n] = *reinterpret_cast<const bf16x8*>(
            &lb[(wc * 32 + n * 16 + (lane & 15)) * 64 + ch]);
      __builtin_amdgcn_s_setprio(1);
#pragma unroll
      for (int m = 0; m < 2; ++m)
#pragma unroll
        for (int n = 0; n < 2; ++n)
          acc[m][n] = __builtin_amdgcn_mfma_f32_16x16x32_bf16(af[m], bfr[n], acc[m][n], 0, 0, 0);
      __builtin_amdgcn_s_setprio(0);
    }
  };

  stage(lA0, lB0, 0);
  for (int k0 = 0; k0 < K; k0 += 128) {   // K % 128 == 0 for all call sites
    __syncthreads();                      // stage(k0) -> buf0 ready
    stage(lA1, lB1, k0 + 64);             // in flight during compute(buf0)
    compute(lA0, lB0);
    __syncthreads();                      // buf1 ready (hidden); buf0 free
    if (k0 + 128 < K) stage(lA0, lB0, k0 + 128);
    compute(lA1, lB1);
  }

  const int r0 = bm + wr * 32, c0 = bn + wc * 32;
#pragma unroll
  for (int m = 0; m < 2; ++m)
#pragma unroll
    for (int n = 0; n < 2; ++n)
#pragma unroll
      for (int r = 0; r < 4; ++r)
        cstore(C, (size_t)(r0 + m * 16 + (lane >> 4) * 4 + r) * N + c0 + n * 16 + (lane & 15),
               acc[m][n][r]);
}

template <typename OutT>
__global__ __launch_bounds__(512, 4) void gemm_bt2(const unsigned short* __restrict__ A,
                                                   const unsigned short* __restrict__ B,
                                                   OutT* __restrict__ C,
                                                   int M, int N, int K) {
  __shared__ unsigned short lA0[128 * 64], lA1[128 * 64];
  __shared__ unsigned short lB0[64 * 64], lB1[64 * 64];
  // T1: XCD-aware block swizzle (nwg % 8 == 0 at every call site)
  unsigned nwg = gridDim.x * gridDim.y;
  unsigned lid = blockIdx.y * gridDim.x + blockIdx.x;
  unsigned swz_id = (lid & 7) * (nwg >> 3) + (lid >> 3);
  const int bm = (int)(swz_id / gridDim.x) * 128;
  const int bn = (int)(swz_id % gridDim.x) * 64;
  gemm_body<OutT>(A, B, C, N, K, bm, bn, lA0, lA1, lB0, lB1);
}

// grouped: blocks [0,1024) -> problem 0 (K0), [1024,2048) -> problem 1 (K1).
// Both M=2048, N=4096 (16 x 64 tile grid per problem).
__global__ __launch_bounds__(512, 4) void gemm_bt2_pair(const unsigned short* __restrict__ A0,
                                                        const unsigned short* __restrict__ B0,
                                                        unsigned short* __restrict__ C0,
                                                        int K0,
                                                        const unsigned short* __restrict__ A1,
                                                        const unsigned short* __restrict__ B1,
                                                        unsigned short* __restrict__ C1,
                                                        int K1) {
  __shared__ unsigned short lA0[128 * 64], lA1[128 * 64];
  __shared__ unsigned short lB0[64 * 64], lB1[64 * 64];
  const int p = blockIdx.x >= 1024;
  unsigned lid = blockIdx.x & 1023;
  unsigned swz_id = (lid & 7) * 128 + (lid >> 3);       // T1 within the half
  const int bm = (int)(swz_id >> 6) * 128;
  const int bn = (int)(swz_id & 63) * 64;
  if (!p)
    gemm_body<unsigned short>(A0, B0, C0, 4096, K0, bm, bn, lA0, lA1, lB0, lB1);
  else
    gemm_body<unsigned short>(A1, B1, C1, 4096, K1, bm, bn, lA0, lA1, lB0, lB1);
}

// ---------------- RMSNorm(q_lat), RMSNorm(c_kv), RoPE(k_rope) ---------------
__global__ __launch_bounds__(256) void rmsnorm_rope(const float* __restrict__ C1,
                                                    const float* __restrict__ qw,
                                                    const float* __restrict__ kvw,
                                                    const float* __restrict__ cosp,
                                                    const float* __restrict__ sinp,
                                                    unsigned short* __restrict__ qn,
                                                    unsigned short* __restrict__ ckvn,
                                                    unsigned short* __restrict__ kr) {
  const int s = blockIdx.x, tid = threadIdx.x;
  const float* row = C1 + (size_t)s * 2048;
  __shared__ float red[4];

  float4 v = *reinterpret_cast<const float4*>(row + tid * 4);
  float ss = v.x * v.x + v.y * v.y + v.z * v.z + v.w * v.w;
  ss += __shfl_xor(ss, 32); ss += __shfl_xor(ss, 16); ss += __shfl_xor(ss, 8);
  ss += __shfl_xor(ss, 4);  ss += __shfl_xor(ss, 2);  ss += __shfl_xor(ss, 1);
  if ((tid & 63) == 0) red[tid >> 6] = ss;
  __syncthreads();
  float rs = rsqrtf((red[0] + red[1] + red[2] + red[3]) * (1.f / 1024.f) + 1e-6f);
  {
    float4 w = *reinterpret_cast<const float4*>(qw + tid * 4);
    *reinterpret_cast<ushort4*>(qn + (size_t)s * 1024 + tid * 4) =
        make_ushort4(f2bf(v.x * rs * w.x), f2bf(v.y * rs * w.y),
                     f2bf(v.z * rs * w.z), f2bf(v.w * rs * w.w));
  }

  float4 u = make_float4(0.f, 0.f, 0.f, 0.f);
  if (tid < 224) u = *reinterpret_cast<const float4*>(row + 1024 + tid * 4);
  ss = u.x * u.x + u.y * u.y + u.z * u.z + u.w * u.w;
  ss += __shfl_xor(ss, 32); ss += __shfl_xor(ss, 16); ss += __shfl_xor(ss, 8);
  ss += __shfl_xor(ss, 4);  ss += __shfl_xor(ss, 2);  ss += __shfl_xor(ss, 1);
  __syncthreads();
  if ((tid & 63) == 0) red[tid >> 6] = ss;
  __syncthreads();
  rs = rsqrtf((red[0] + red[1] + red[2] + red[3]) * (1.f / 896.f) + 1e-6f);
  if (tid < 224) {
    float4 w = *reinterpret_cast<const float4*>(kvw + tid * 4);
    *reinterpret_cast<ushort4*>(ckvn + (size_t)s * 896 + tid * 4) =
        make_ushort4(f2bf(u.x * rs * w.x), f2bf(u.y * rs * w.y),
                     f2bf(u.z * rs * w.z), f2bf(u.w * rs * w.w));
  }

  if (tid < 64) {
    int d = tid;
    float x = row[1920 + d];
    float part = (d < 32) ? -row[1920 + d + 32] : row[1920 + d - 32];
    float vv = x * cosp[(size_t)s * 64 + d] + part * sinp[(size_t)s * 64 + d];
    kr[(size_t)s * 64 + d] = f2bf(vv);
  }
}

// ---------------- KV post: Vt = V^T (pure bf16 transpose) -------------------
__global__ __launch_bounds__(256) void kv_post(const unsigned short* __restrict__ KVfb,
                                               unsigned short* __restrict__ Vt) {
  __shared__ unsigned short lT[64 * 65];
  const int s0 = blockIdx.x * 64, h = blockIdx.y, tid = threadIdx.x;
  for (int idx = tid; idx < 4096; idx += 256) {
    int r = idx >> 6, c = idx & 63;
    lT[r * 65 + c] = KVfb[(size_t)(s0 + r) * 4096 + h * 128 + 64 + c];
  }
  __syncthreads();
  for (int idx = tid; idx < 4096; idx += 256) {
    int d = idx >> 6, c = idx & 63;
    Vt[((size_t)h * 64 + d) * 2048 + s0 + c] = lT[c * 65 + d];
  }
}

// ---------------- flash attention (causal, 2-way key-split partials) --------
// grid (32 heads, 64): qb = 31-(y>>1) (LPT), j = y&1; tiles t%2==j, t<=qb.
// 5 blocks/CU (LDS 32KB exactly). Q-load fused RoPE+SCALE*log2e; K staged
// straight from KVfb (nope) + kr (rope) via per-lane gload_lds source select.
__global__ __launch_bounds__(256, 5) void flash_attn(const unsigned short* __restrict__ Qfb,
                                                     const unsigned short* __restrict__ KVfb,
                                                     const unsigned short* __restrict__ kr,
                                                     const float* __restrict__ cosp,
                                                     const float* __restrict__ sinp,
                                                     const unsigned short* __restrict__ Vt,
                                                     float* __restrict__ Op,
                                                     float2* __restrict__ Ml) {
  __shared__ unsigned short lK0[64 * 128], lK1[64 * 128];
  const int tid = threadIdx.x, lane = tid & 63, wv = tid >> 6;
  const int h = blockIdx.x;
  const int qb = 31 - ((int)blockIdx.y >> 1);            // LPT: heavy first
  const int j = (int)blockIdx.y & 1;                     // key-split half
  const int q0 = qb * 64;
  const int firstrow = q0 + wv * 16;
  const int g = lane >> 4;
  const int qa = firstrow + (lane & 15);                 // this lane's q-row
  const float SC = 0.18033688f;                          // 0.125 * log2(e)

  // ---- Q load + fused RoPE + scale (once per block) ----
  bf16x8 qf[4];
  {
    const unsigned short* qr = Qfb + (size_t)qa * 4096 + h * 128;
    float raw[4][8];
#pragma unroll
    for (int ks = 0; ks < 4; ++ks) {
      ushort4 u0 = *reinterpret_cast<const ushort4*>(qr + ks * 32 + g * 8);
      ushort4 u1 = *reinterpret_cast<const ushort4*>(qr + ks * 32 + g * 8 + 4);
      raw[ks][0] = bf2f(u0.x); raw[ks][1] = bf2f(u0.y);
      raw[ks][2] = bf2f(u0.z); raw[ks][3] = bf2f(u0.w);
      raw[ks][4] = bf2f(u1.x); raw[ks][5] = bf2f(u1.y);
      raw[ks][6] = bf2f(u1.z); raw[ks][7] = bf2f(u1.w);
    }
    const float* cp = cosp + (size_t)qa * 64 + g * 8;
    const float* sp = sinp + (size_t)qa * 64 + g * 8;
    float c0[8], s0[8], c1[8], s1[8];
    {
      float4 a = *reinterpret_cast<const float4*>(cp);
      float4 b = *reinterpret_cast<const float4*>(cp + 4);
      c0[0]=a.x;c0[1]=a.y;c0[2]=a.z;c0[3]=a.w;c0[4]=b.x;c0[5]=b.y;c0[6]=b.z;c0[7]=b.w;
      a = *reinterpret_cast<const float4*>(cp + 32);
      b = *reinterpret_cast<const float4*>(cp + 36);
      c1[0]=a.x;c1[1]=a.y;c1[2]=a.z;c1[3]=a.w;c1[4]=b.x;c1[5]=b.y;c1[6]=b.z;c1[7]=b.w;
      a = *reinterpret_cast<const float4*>(sp);
      b = *reinterpret_cast<const float4*>(sp + 4);
      s0[0]=a.x;s0[1]=a.y;s0[2]=a.z;s0[3]=a.w;s0[4]=b.x;s0[5]=b.y;s0[6]=b.z;s0[7]=b.w;
      a = *reinterpret_cast<const float4*>(sp + 32);
      b = *reinterpret_cast<const float4*>(sp + 36);
      s1[0]=a.x;s1[1]=a.y;s1[2]=a.z;s1[3]=a.w;s1[4]=b.x;s1[5]=b.y;s1[6]=b.z;s1[7]=b.w;
    }
    alignas(16) unsigned short pk[4][8];
#pragma unroll
    for (int e = 0; e < 8; ++e) {
      pk[0][e] = f2bf(raw[0][e] * SC);
      pk[1][e] = f2bf(raw[1][e] * SC);
      pk[2][e] = f2bf((raw[2][e] * c0[e] - raw[3][e] * s0[e]) * SC);
      pk[3][e] = f2bf((raw[3][e] * c1[e] + raw[2][e] * s1[e]) * SC);
    }
#pragma unroll
    for (int ks = 0; ks < 4; ++ks)
      qf[ks] = *reinterpret_cast<const bf16x8*>(pk[ks]);
  }

  f32x4 o_acc[4] = {};
  float mrow = -1e30f, lrow = 0.f;   // per-lane: stats of q-row qa

  const int sl0 = ((g & 1) * 2) * 16 + (lane & 15);   // src lane, m=0,1
  const int sl1 = sl0 + 16;                           // src lane, m=2,3
  const bool hi = g >= 2;                             // selects src_n = 2ks+1

  const int krow = wv * 4 + (lane >> 4);
  const int cs = (lane & 15) ^ (krow & 7);            // swizzled source chunk
  const int swz = lane & 7;                           // read-side row&7

  auto stage = [&](int t, unsigned short* lK) {
    int jj = t * 64;
#pragma unroll
    for (int i = 0; i < 4; ++i) {
      int s = jj + i * 16 + krow;
      const unsigned short* src =
          (cs < 8) ? KVfb + (size_t)s * 4096 + h * 128 + cs * 8
                   : kr + (size_t)s * 64 + (cs - 8) * 8;
      gload_lds16(src, &lK[(i * 16 + wv * 4) * 128]);
    }
  };

  auto loadV = [&](int j0, bf16x8 (&vr)[2][4]) {
#pragma unroll
    for (int ks = 0; ks < 2; ++ks)
#pragma unroll
      for (int n = 0; n < 4; ++n)
        vr[ks][n] = *reinterpret_cast<const bf16x8*>(
            Vt + ((size_t)h * 64 + n * 16 + (lane & 15)) * 2048 + j0 + ks * 32 +
            (lane >> 4) * 8);
  };

  auto computeT = [&](int j0, const unsigned short* lK, const bf16x8 (&vr)[2][4]) {
    f32x4 sT[4] = {};
    __builtin_amdgcn_s_setprio(1);
#pragma unroll
    for (int n = 0; n < 4; ++n)
#pragma unroll
      for (int ks = 0; ks < 4; ++ks) {
        bf16x8 kf = *reinterpret_cast<const bf16x8*>(
            &lK[(n * 16 + (lane & 15)) * 128 + (((ks * 4 + (lane >> 4)) ^ swz)) * 8]);
        sT[n] = __builtin_amdgcn_mfma_f32_16x16x32_bf16(kf, qf[ks], sT[n], 0, 0, 0);
      }
    __builtin_amdgcn_s_setprio(0);

    if (j0 == q0) {  // diagonal tile: causal mask
#pragma unroll
      for (int n = 0; n < 4; ++n)
#pragma unroll
        for (int r = 0; r < 4; ++r) {
          int key = j0 + n * 16 + g * 4 + r;
          if (key > qa) sT[n][r] = -1e30f;
        }
    }

    // tree max over 16 values + 2 shfl
    float tm[4];
#pragma unroll
    for (int n = 0; n < 4; ++n)
      tm[n] = fmaxf(fmaxf(sT[n][0], sT[n][1]), fmaxf(sT[n][2], sT[n][3]));
    float mx = fmaxf(fmaxf(tm[0], tm[1]), fmaxf(tm[2], tm[3]));
    mx = fmaxf(mx, __shfl_xor(mx, 16));
    mx = fmaxf(mx, __shfl_xor(mx, 32));

    if (__any(mx - mrow > 8.0f)) {   // defer-max (T13), exp2 domain
      float mn = fmaxf(mrow, mx);
      float sf = exp2f(mrow - mn);
      mrow = mn;
      lrow *= sf;
      float sfr[4];
#pragma unroll
      for (int r = 0; r < 4; ++r) sfr[r] = __shfl(sf, (lane >> 4) * 4 + r);
#pragma unroll
      for (int n = 0; n < 4; ++n)
#pragma unroll
        for (int r = 0; r < 4; ++r) o_acc[n][r] *= sfr[r];
    }

    float psn[4];
    unsigned dw[4][2];
#pragma unroll
    for (int n = 0; n < 4; ++n) {
      float p0 = exp2f(sT[n][0] - mrow), p1 = exp2f(sT[n][1] - mrow);
      float p2 = exp2f(sT[n][2] - mrow), p3 = exp2f(sT[n][3] - mrow);
      psn[n] = (p0 + p1) + (p2 + p3);
      asm("v_cvt_pk_bf16_f32 %0, %1, %2" : "=v"(dw[n][0]) : "v"(p0), "v"(p1));
      asm("v_cvt_pk_bf16_f32 %0, %1, %2" : "=v"(dw[n][1]) : "v"(p2), "v"(p3));
    }
    float ps = (psn[0] + psn[1]) + (psn[2] + psn[3]);
    ps += __shfl_xor(ps, 16);
    ps += __shfl_xor(ps, 32);
    lrow += ps;

#pragma unroll
    for (int ks = 0; ks < 2; ++ks) {
      unsigned A0 = __shfl(dw[2 * ks][0], sl0);
      unsigned B0 = __shfl(dw[2 * ks + 1][0], sl0);
      unsigned A1 = __shfl(dw[2 * ks][1], sl0);
      unsigned B1 = __shfl(dw[2 * ks + 1][1], sl0);
      unsigned A2 = __shfl(dw[2 * ks][0], sl1);
      unsigned B2 = __shfl(dw[2 * ks + 1][0], sl1);
      unsigned A3 = __shfl(dw[2 * ks][1], sl1);
      unsigned B3 = __shfl(dw[2 * ks + 1][1], sl1);
      u32x4 mm;
      mm.x = hi ? B0 : A0; mm.y = hi ? B1 : A1;
      mm.z = hi ? B2 : A2; mm.w = hi ? B3 : A3;
      bf16x8 pa = __builtin_bit_cast(bf16x8, mm);
      __builtin_amdgcn_s_setprio(1);
#pragma unroll
      for (int n = 0; n < 4; ++n)
        o_acc[n] = __builtin_amdgcn_mfma_f32_16x16x32_bf16(pa, vr[ks][n], o_acc[n], 0, 0, 0);
      __builtin_amdgcn_s_setprio(0);
    }
  };

  // tiles t = j, j+2, ..., <= qb  (empty for qb=0,j=1: falls through)
  bf16x8 vr[2][4];
  unsigned short* cur = lK0;
  unsigned short* nxt = lK1;
  if (j <= qb) stage(j, cur);
  for (int t = j; t <= qb; t += 2) {
    __syncthreads();                         // cur ready (stage issued 1 compute ago)
    if (t + 2 <= qb) stage(t + 2, nxt);      // lands under computeT(t)
    loadV(t * 64, vr);                       // consumed at PV; hides under QK^T
    computeT(t * 64, cur, vr);
    unsigned short* tmp = cur; cur = nxt; nxt = tmp;
  }

  // partial epilogue: unnormalized O (f32) + (m,l) per q-row
  float* op = Op + (size_t)j * 4194304 + ((size_t)h * 2048 + firstrow) * 64;
#pragma unroll
  for (int n = 0; n < 4; ++n)
#pragma unroll
    for (int r = 0; r < 4; ++r)
      op[(size_t)(g * 4 + r) * 64 + n * 16 + (lane & 15)] = o_acc[n][r];
  if (lane < 16)
    Ml[(size_t)j * 65536 + h * 2048 + qa] = make_float2(mrow, lrow);
}

// ---------------- flash combine: LSE-merge the two partials -----------------
__global__ __launch_bounds__(256) void flash_combine(const float* __restrict__ Op,
                                                     const float2* __restrict__ Ml,
                                                     unsigned short* __restrict__ Ao) {
  size_t i4 = ((size_t)blockIdx.x * 256 + threadIdx.x) * 4;  // over 2048*2048
  int s = (int)(i4 >> 11);
  int c = (int)(i4 & 2047);
  int h = c >> 6, d = c & 63;
  float2 a = Ml[h * 2048 + s];
  float2 b = Ml[65536 + h * 2048 + s];
  float M = fmaxf(a.x, b.x);
  float w0 = exp2f(a.x - M), w1 = exp2f(b.x - M);
  float inv = 1.f / (w0 * a.y + w1 * b.y);
  size_t pidx = ((size_t)h * 2048 + s) * 64 + d;
  float4 o0 = *reinterpret_cast<const float4*>(Op + pidx);
  float4 o1 = *reinterpret_cast<const float4*>(Op + 4194304 + pidx);
  *reinterpret_cast<ushort4*>(Ao + (size_t)s * 2048 + h * 64 + d) =
      make_ushort4(f2bf((w0 * o0.x + w1 * o1.x) * inv),
                   f2bf((w0 * o0.y + w1 * o1.y) * inv),
                   f2bf((w0 * o0.z + w1 * o1.z) * inv),
                   f2bf((w0 * o0.w + w1 * o1.w) * inv));
}

// ---------------------------------------------------------------------------
extern "C" void kernel_launch(void* const* d_in, const int* in_sizes, int n_in,
                              void* d_out, int out_size, void* d_ws, size_t ws_size,
                              hipStream_t stream) {
  const float* hs   = (const float*)d_in[0];
  const float* cosp = (const float*)d_in[1];
  const float* sinp = (const float*)d_in[2];
  const float* qaw  = (const float*)d_in[3];
  const float* qaln = (const float*)d_in[4];
  const float* qbwf = (const float*)d_in[5];
  const float* kvaw = (const float*)d_in[6];
  const float* kvln = (const float*)d_in[7];
  const float* kvbwf= (const float*)d_in[8];
  const float* owf  = (const float*)d_in[9];
  float* out = (float*)d_out;
  char* ws = (char*)d_ws;
  const size_t MB = 1u << 20;

  // overlay map (lifetimes):
  unsigned short* W1b  = (unsigned short*)(ws + 0);        // 8 MB   [dead after gemm1]
  unsigned short* Ao   = (unsigned short*)(ws + 0);        // 8 MB   (combine out)
  unsigned short* qbw  = (unsigned short*)(ws + 8 * MB);   // 8 MB   [dead after gemm2]
  unsigned short* Vt   = (unsigned short*)(ws + 8 * MB);   // 8 MB   (kv_post out)
  unsigned short* kvbw = (unsigned short*)(ws + 16 * MB);  // 7 MB   [dead after gemm2]
  unsigned short* owb  = (unsigned short*)(ws + 23 * MB);  // 8 MB
  unsigned short* hsb  = (unsigned short*)(ws + 31 * MB);  // 8 MB   [dead after gemm1]
  unsigned short* Qfb  = (unsigned short*)(ws + 31 * MB);  // 16 MB  (gemm2 out, raw Q bf16)
  float*          C1   = (float*)(ws + 47 * MB);           // 16 MB  [dead after rmsnorm]
  unsigned short* KVfb = (unsigned short*)(ws + 63 * MB);  // 16 MB  (gemm2 out bf16)
  unsigned short* kr   = (unsigned short*)(ws + 79 * MB);  // 0.25 MB
  unsigned short* qln  = (unsigned short*)(ws + 80 * MB);  // 4 MB   [dead after gemm2]
  unsigned short* ckvn = (unsigned short*)(ws + 84 * MB);  // 3.5 MB [dead after gemm2]
  float*          Op   = (float*)(ws + 88 * MB);           // 2x16.78 MB (flash partials)
  float2*         Mlp  = (float2*)(ws + 122 * MB);         // 2x0.5 MB
  (void)ws_size; (void)in_sizes; (void)n_in; (void)out_size;

  // ---- one fused convert launch (6 segments) ----
  CvtSegs sg;
  sg.src[0] = qaw;   sg.dst[0] = W1b;                      sg.n_src[0] = 1024u * 2048u; sg.n_tot[0] = 1024u * 2048u;
  sg.src[1] = kvaw;  sg.dst[1] = W1b + (size_t)1024 * 2048; sg.n_src[1] = 960u * 2048u;  sg.n_tot[1] = 1024u * 2048u;
  sg.src[2] = hs;    sg.dst[2] = hsb;                      sg.n_src[2] = 2048u * 2048u; sg.n_tot[2] = 2048u * 2048u;
  sg.src[3] = qbwf;  sg.dst[3] = qbw;                      sg.n_src[3] = 4096u * 1024u; sg.n_tot[3] = 4096u * 1024u;
  sg.src[4] = kvbwf; sg.dst[4] = kvbw;                     sg.n_src[4] = 4096u * 896u;  sg.n_tot[4] = 4096u * 896u;
  sg.src[5] = owf;   sg.dst[5] = owb;                      sg.n_src[5] = 2048u * 2048u; sg.n_tot[5] = 2048u * 2048u;
  sg.blk0[0] = 0;
  for (int k = 0; k < 6; ++k) sg.blk0[k + 1] = sg.blk0[k] + sg.n_tot[k] / 1024u;
  cvt_all<<<dim3(sg.blk0[6]), 256, 0, stream>>>(sg);

  gemm_bt2<float><<<dim3(32, 16), 512, 0, stream>>>(hsb, W1b, C1, 2048, 2048, 2048);
  rmsnorm_rope<<<2048, 256, 0, stream>>>(C1, qaln, kvln, cosp, sinp, qln, ckvn, kr);

  // grouped: Qfb = qln @ qbw^T  and  KVfb = ckvn @ kvbw^T  in one launch
  gemm_bt2_pair<<<dim3(2048), 512, 0, stream>>>(qln, qbw, Qfb, 1024,
                                                ckvn, kvbw, KVfb, 896);

  kv_post<<<dim3(32, 32), 256, 0, stream>>>(KVfb, Vt);

  flash_attn<<<dim3(32, 64), 256, 0, stream>>>(Qfb, KVfb, kr, cosp, sinp, Vt, Op, Mlp);
  flash_combine<<<dim3(4096), 256, 0, stream>>>(Op, Mlp, Ao);

  gemm_bt2<float><<<dim3(32, 16), 512, 0, stream>>>(Ao, owb, out, 2048, 2048, 2048);
}

// Round 14
// 216.110 us; speedup vs baseline: 1.2612x; 1.2612x over previous
//
#include <hip/hip_runtime.h>

// ---------------------------------------------------------------------------
// MLA (LoraQKV) pipeline for MI355X, bf16 MFMA everywhere.
//   1) cvt_all; 2) gemm C1 = hs@W1^T (f32); 3) rmsnorm_rope;
//   4) grouped gemm Qfb+KVfb (bf16 out, one launch); 5) kv_post (V^T);
//   6) flash_attn (Q-RoPE fused, K from KVfb+kr, 2-way key-split) + combine;
//   7) gemm out = Ao@o_w^T (f32).
// R14: revert R13's flash __launch_bounds__(256,5) -> (256,4). The 5-block
//     bound forced VGPR 64->48 => scratch spills (FETCH 24->100MB, flash
//     97->158us). Keep the grouped gemm2 pair (it was the winning half).
// ---------------------------------------------------------------------------

typedef __attribute__((ext_vector_type(8))) __bf16 bf16x8;
typedef __attribute__((ext_vector_type(4))) float f32x4;
typedef __attribute__((ext_vector_type(4))) unsigned u32x4;

__device__ __forceinline__ unsigned short f2bf(float f) {
  unsigned int x = __builtin_bit_cast(unsigned int, f);
  x += 0x7fffu + ((x >> 16) & 1u);
  return (unsigned short)(x >> 16);
}
__device__ __forceinline__ float bf2f(unsigned short u) {
  unsigned int x = ((unsigned int)u) << 16;
  return __builtin_bit_cast(float, x);
}
__device__ __forceinline__ void gload_lds16(const void* g, void* l) {
  __builtin_amdgcn_global_load_lds(
      (const __attribute__((address_space(1))) void*)g,
      (__attribute__((address_space(3))) void*)l, 16, 0, 0);
}
__device__ __forceinline__ void cstore(float* C, size_t i, float v) { C[i] = v; }
__device__ __forceinline__ void cstore(unsigned short* C, size_t i, float v) { C[i] = f2bf(v); }

// ---------------- segmented convert (all f32->bf16 converts in one launch) --
struct CvtSegs {
  const float* src[6];
  unsigned short* dst[6];
  unsigned int n_src[6];
  unsigned int n_tot[6];
  unsigned int blk0[7];
};

__global__ __launch_bounds__(256) void cvt_all(CvtSegs sg) {
  int b = blockIdx.x;
  int seg = 0;
#pragma unroll
  for (int k = 0; k < 5; ++k)
    if (b >= (int)sg.blk0[k + 1]) seg = k + 1;
  size_t i = ((size_t)(b - sg.blk0[seg]) * 256 + threadIdx.x) * 4;
  if (i >= sg.n_tot[seg]) return;
  unsigned short o0 = 0, o1 = 0, o2 = 0, o3 = 0;
  if (i < sg.n_src[seg]) {
    float4 v = *reinterpret_cast<const float4*>(sg.src[seg] + i);
    o0 = f2bf(v.x); o1 = f2bf(v.y); o2 = f2bf(v.z); o3 = f2bf(v.w);
  }
  *reinterpret_cast<ushort4*>(sg.dst[seg] + i) = make_ushort4(o0, o1, o2, o3);
}

// ---------------- GEMM core (shared by single and grouped kernels) ----------
// 128x64 tile, BK=64, 512 threads (8 waves 4x2, wave tile 32x32), dbuf LDS,
// 2-phase; T2 swizzle via pre-swizzled gload source.
template <typename OutT>
__device__ __forceinline__ void gemm_body(const unsigned short* __restrict__ A,
                                          const unsigned short* __restrict__ B,
                                          OutT* __restrict__ C,
                                          int N, int K, int bm, int bn,
                                          unsigned short* lA0, unsigned short* lA1,
                                          unsigned short* lB0, unsigned short* lB1) {
  const int tid = threadIdx.x, lane = tid & 63, wv = tid >> 6;
  const int wr = wv >> 1, wc = wv & 1;             // 4x2 wave grid

  f32x4 acc[2][2] = {};

  const int ar0 = tid >> 3;
  const int acol = (((tid & 7) ^ ((tid >> 3) & 7))) * 8;   // T2 pre-swizzled src
  const int swz = lane & 7;

  auto stage = [&](unsigned short* la, unsigned short* lb, int k0) {
#pragma unroll
    for (int i = 0; i < 2; ++i)
      gload_lds16(A + (size_t)(bm + i * 64 + ar0) * K + k0 + acol,
                  &la[(i * 512 + wv * 64) * 8]);
    gload_lds16(B + (size_t)(bn + ar0) * K + k0 + acol, &lb[(wv * 64) * 8]);
  };

  auto compute = [&](const unsigned short* la, const unsigned short* lb) {
#pragma unroll
    for (int ks = 0; ks < 2; ++ks) {
      const int ch = ((ks * 4 + (lane >> 4)) ^ swz) * 8;
      bf16x8 af[2], bfr[2];
#pragma unroll
      for (int m = 0; m < 2; ++m)
        af[m] = *reinterpret_cast<const bf16x8*>(
            &la[(wr * 32 + m * 16 + (lane & 15)) * 64 + ch]);
#pragma unroll
      for (int n = 0; n < 2; ++n)
        bfr[n] = *reinterpret_cast<const bf16x8*>(
            &lb[(wc * 32 + n * 16 + (lane & 15)) * 64 + ch]);
      __builtin_amdgcn_s_setprio(1);
#pragma unroll
      for (int m = 0; m < 2; ++m)
#pragma unroll
        for (int n = 0; n < 2; ++n)
          acc[m][n] = __builtin_amdgcn_mfma_f32_16x16x32_bf16(af[m], bfr[n], acc[m][n], 0, 0, 0);
      __builtin_amdgcn_s_setprio(0);
    }
  };

  stage(lA0, lB0, 0);
  for (int k0 = 0; k0 < K; k0 += 128) {   // K % 128 == 0 for all call sites
    __syncthreads();                      // stage(k0) -> buf0 ready
    stage(lA1, lB1, k0 + 64);             // in flight during compute(buf0)
    compute(lA0, lB0);
    __syncthreads();                      // buf1 ready (hidden); buf0 free
    if (k0 + 128 < K) stage(lA0, lB0, k0 + 128);
    compute(lA1, lB1);
  }

  const int r0 = bm + wr * 32, c0 = bn + wc * 32;
#pragma unroll
  for (int m = 0; m < 2; ++m)
#pragma unroll
    for (int n = 0; n < 2; ++n)
#pragma unroll
      for (int r = 0; r < 4; ++r)
        cstore(C, (size_t)(r0 + m * 16 + (lane >> 4) * 4 + r) * N + c0 + n * 16 + (lane & 15),
               acc[m][n][r]);
}

template <typename OutT>
__global__ __launch_bounds__(512, 4) void gemm_bt2(const unsigned short* __restrict__ A,
                                                   const unsigned short* __restrict__ B,
                                                   OutT* __restrict__ C,
                                                   int M, int N, int K) {
  __shared__ unsigned short lA0[128 * 64], lA1[128 * 64];
  __shared__ unsigned short lB0[64 * 64], lB1[64 * 64];
  // T1: XCD-aware block swizzle (nwg % 8 == 0 at every call site)
  unsigned nwg = gridDim.x * gridDim.y;
  unsigned lid = blockIdx.y * gridDim.x + blockIdx.x;
  unsigned swz_id = (lid & 7) * (nwg >> 3) + (lid >> 3);
  const int bm = (int)(swz_id / gridDim.x) * 128;
  const int bn = (int)(swz_id % gridDim.x) * 64;
  gemm_body<OutT>(A, B, C, N, K, bm, bn, lA0, lA1, lB0, lB1);
}

// grouped: blocks [0,1024) -> problem 0 (K0), [1024,2048) -> problem 1 (K1).
// Both M=2048, N=4096 (16 x 64 tile grid per problem).
__global__ __launch_bounds__(512, 4) void gemm_bt2_pair(const unsigned short* __restrict__ A0,
                                                        const unsigned short* __restrict__ B0,
                                                        unsigned short* __restrict__ C0,
                                                        int K0,
                                                        const unsigned short* __restrict__ A1,
                                                        const unsigned short* __restrict__ B1,
                                                        unsigned short* __restrict__ C1,
                                                        int K1) {
  __shared__ unsigned short lA0[128 * 64], lA1[128 * 64];
  __shared__ unsigned short lB0[64 * 64], lB1[64 * 64];
  const int p = blockIdx.x >= 1024;
  unsigned lid = blockIdx.x & 1023;
  unsigned swz_id = (lid & 7) * 128 + (lid >> 3);       // T1 within the half
  const int bm = (int)(swz_id >> 6) * 128;
  const int bn = (int)(swz_id & 63) * 64;
  if (!p)
    gemm_body<unsigned short>(A0, B0, C0, 4096, K0, bm, bn, lA0, lA1, lB0, lB1);
  else
    gemm_body<unsigned short>(A1, B1, C1, 4096, K1, bm, bn, lA0, lA1, lB0, lB1);
}

// ---------------- RMSNorm(q_lat), RMSNorm(c_kv), RoPE(k_rope) ---------------
__global__ __launch_bounds__(256) void rmsnorm_rope(const float* __restrict__ C1,
                                                    const float* __restrict__ qw,
                                                    const float* __restrict__ kvw,
                                                    const float* __restrict__ cosp,
                                                    const float* __restrict__ sinp,
                                                    unsigned short* __restrict__ qn,
                                                    unsigned short* __restrict__ ckvn,
                                                    unsigned short* __restrict__ kr) {
  const int s = blockIdx.x, tid = threadIdx.x;
  const float* row = C1 + (size_t)s * 2048;
  __shared__ float red[4];

  float4 v = *reinterpret_cast<const float4*>(row + tid * 4);
  float ss = v.x * v.x + v.y * v.y + v.z * v.z + v.w * v.w;
  ss += __shfl_xor(ss, 32); ss += __shfl_xor(ss, 16); ss += __shfl_xor(ss, 8);
  ss += __shfl_xor(ss, 4);  ss += __shfl_xor(ss, 2);  ss += __shfl_xor(ss, 1);
  if ((tid & 63) == 0) red[tid >> 6] = ss;
  __syncthreads();
  float rs = rsqrtf((red[0] + red[1] + red[2] + red[3]) * (1.f / 1024.f) + 1e-6f);
  {
    float4 w = *reinterpret_cast<const float4*>(qw + tid * 4);
    *reinterpret_cast<ushort4*>(qn + (size_t)s * 1024 + tid * 4) =
        make_ushort4(f2bf(v.x * rs * w.x), f2bf(v.y * rs * w.y),
                     f2bf(v.z * rs * w.z), f2bf(v.w * rs * w.w));
  }

  float4 u = make_float4(0.f, 0.f, 0.f, 0.f);
  if (tid < 224) u = *reinterpret_cast<const float4*>(row + 1024 + tid * 4);
  ss = u.x * u.x + u.y * u.y + u.z * u.z + u.w * u.w;
  ss += __shfl_xor(ss, 32); ss += __shfl_xor(ss, 16); ss += __shfl_xor(ss, 8);
  ss += __shfl_xor(ss, 4);  ss += __shfl_xor(ss, 2);  ss += __shfl_xor(ss, 1);
  __syncthreads();
  if ((tid & 63) == 0) red[tid >> 6] = ss;
  __syncthreads();
  rs = rsqrtf((red[0] + red[1] + red[2] + red[3]) * (1.f / 896.f) + 1e-6f);
  if (tid < 224) {
    float4 w = *reinterpret_cast<const float4*>(kvw + tid * 4);
    *reinterpret_cast<ushort4*>(ckvn + (size_t)s * 896 + tid * 4) =
        make_ushort4(f2bf(u.x * rs * w.x), f2bf(u.y * rs * w.y),
                     f2bf(u.z * rs * w.z), f2bf(u.w * rs * w.w));
  }

  if (tid < 64) {
    int d = tid;
    float x = row[1920 + d];
    float part = (d < 32) ? -row[1920 + d + 32] : row[1920 + d - 32];
    float vv = x * cosp[(size_t)s * 64 + d] + part * sinp[(size_t)s * 64 + d];
    kr[(size_t)s * 64 + d] = f2bf(vv);
  }
}

// ---------------- KV post: Vt = V^T (pure bf16 transpose) -------------------
__global__ __launch_bounds__(256) void kv_post(const unsigned short* __restrict__ KVfb,
                                               unsigned short* __restrict__ Vt) {
  __shared__ unsigned short lT[64 * 65];
  const int s0 = blockIdx.x * 64, h = blockIdx.y, tid = threadIdx.x;
  for (int idx = tid; idx < 4096; idx += 256) {
    int r = idx >> 6, c = idx & 63;
    lT[r * 65 + c] = KVfb[(size_t)(s0 + r) * 4096 + h * 128 + 64 + c];
  }
  __syncthreads();
  for (int idx = tid; idx < 4096; idx += 256) {
    int d = idx >> 6, c = idx & 63;
    Vt[((size_t)h * 64 + d) * 2048 + s0 + c] = lT[c * 65 + d];
  }
}

// ---------------- flash attention (causal, 2-way key-split partials) --------
// grid (32 heads, 64): qb = 31-(y>>1) (LPT), j = y&1; tiles t%2==j, t<=qb.
// 4 blocks/CU (VGPR 64 fits, no spill). Q-load fused RoPE+SCALE*log2e; K
// staged straight from KVfb (nope) + kr (rope) via per-lane source select.
__global__ __launch_bounds__(256, 4) void flash_attn(const unsigned short* __restrict__ Qfb,
                                                     const unsigned short* __restrict__ KVfb,
                                                     const unsigned short* __restrict__ kr,
                                                     const float* __restrict__ cosp,
                                                     const float* __restrict__ sinp,
                                                     const unsigned short* __restrict__ Vt,
                                                     float* __restrict__ Op,
                                                     float2* __restrict__ Ml) {
  __shared__ unsigned short lK0[64 * 128], lK1[64 * 128];
  const int tid = threadIdx.x, lane = tid & 63, wv = tid >> 6;
  const int h = blockIdx.x;
  const int qb = 31 - ((int)blockIdx.y >> 1);            // LPT: heavy first
  const int j = (int)blockIdx.y & 1;                     // key-split half
  const int q0 = qb * 64;
  const int firstrow = q0 + wv * 16;
  const int g = lane >> 4;
  const int qa = firstrow + (lane & 15);                 // this lane's q-row
  const float SC = 0.18033688f;                          // 0.125 * log2(e)

  // ---- Q load + fused RoPE + scale (once per block) ----
  bf16x8 qf[4];
  {
    const unsigned short* qr = Qfb + (size_t)qa * 4096 + h * 128;
    float raw[4][8];
#pragma unroll
    for (int ks = 0; ks < 4; ++ks) {
      ushort4 u0 = *reinterpret_cast<const ushort4*>(qr + ks * 32 + g * 8);
      ushort4 u1 = *reinterpret_cast<const ushort4*>(qr + ks * 32 + g * 8 + 4);
      raw[ks][0] = bf2f(u0.x); raw[ks][1] = bf2f(u0.y);
      raw[ks][2] = bf2f(u0.z); raw[ks][3] = bf2f(u0.w);
      raw[ks][4] = bf2f(u1.x); raw[ks][5] = bf2f(u1.y);
      raw[ks][6] = bf2f(u1.z); raw[ks][7] = bf2f(u1.w);
    }
    const float* cp = cosp + (size_t)qa * 64 + g * 8;
    const float* sp = sinp + (size_t)qa * 64 + g * 8;
    float c0[8], s0[8], c1[8], s1[8];
    {
      float4 a = *reinterpret_cast<const float4*>(cp);
      float4 b = *reinterpret_cast<const float4*>(cp + 4);
      c0[0]=a.x;c0[1]=a.y;c0[2]=a.z;c0[3]=a.w;c0[4]=b.x;c0[5]=b.y;c0[6]=b.z;c0[7]=b.w;
      a = *reinterpret_cast<const float4*>(cp + 32);
      b = *reinterpret_cast<const float4*>(cp + 36);
      c1[0]=a.x;c1[1]=a.y;c1[2]=a.z;c1[3]=a.w;c1[4]=b.x;c1[5]=b.y;c1[6]=b.z;c1[7]=b.w;
      a = *reinterpret_cast<const float4*>(sp);
      b = *reinterpret_cast<const float4*>(sp + 4);
      s0[0]=a.x;s0[1]=a.y;s0[2]=a.z;s0[3]=a.w;s0[4]=b.x;s0[5]=b.y;s0[6]=b.z;s0[7]=b.w;
      a = *reinterpret_cast<const float4*>(sp + 32);
      b = *reinterpret_cast<const float4*>(sp + 36);
      s1[0]=a.x;s1[1]=a.y;s1[2]=a.z;s1[3]=a.w;s1[4]=b.x;s1[5]=b.y;s1[6]=b.z;s1[7]=b.w;
    }
    alignas(16) unsigned short pk[4][8];
#pragma unroll
    for (int e = 0; e < 8; ++e) {
      pk[0][e] = f2bf(raw[0][e] * SC);
      pk[1][e] = f2bf(raw[1][e] * SC);
      pk[2][e] = f2bf((raw[2][e] * c0[e] - raw[3][e] * s0[e]) * SC);
      pk[3][e] = f2bf((raw[3][e] * c1[e] + raw[2][e] * s1[e]) * SC);
    }
#pragma unroll
    for (int ks = 0; ks < 4; ++ks)
      qf[ks] = *reinterpret_cast<const bf16x8*>(pk[ks]);
  }

  f32x4 o_acc[4] = {};
  float mrow = -1e30f, lrow = 0.f;   // per-lane: stats of q-row qa

  const int sl0 = ((g & 1) * 2) * 16 + (lane & 15);   // src lane, m=0,1
  const int sl1 = sl0 + 16;                           // src lane, m=2,3
  const bool hi = g >= 2;                             // selects src_n = 2ks+1

  const int krow = wv * 4 + (lane >> 4);
  const int cs = (lane & 15) ^ (krow & 7);            // swizzled source chunk
  const int swz = lane & 7;                           // read-side row&7

  auto stage = [&](int t, unsigned short* lK) {
    int jj = t * 64;
#pragma unroll
    for (int i = 0; i < 4; ++i) {
      int s = jj + i * 16 + krow;
      const unsigned short* src =
          (cs < 8) ? KVfb + (size_t)s * 4096 + h * 128 + cs * 8
                   : kr + (size_t)s * 64 + (cs - 8) * 8;
      gload_lds16(src, &lK[(i * 16 + wv * 4) * 128]);
    }
  };

  auto loadV = [&](int j0, bf16x8 (&vr)[2][4]) {
#pragma unroll
    for (int ks = 0; ks < 2; ++ks)
#pragma unroll
      for (int n = 0; n < 4; ++n)
        vr[ks][n] = *reinterpret_cast<const bf16x8*>(
            Vt + ((size_t)h * 64 + n * 16 + (lane & 15)) * 2048 + j0 + ks * 32 +
            (lane >> 4) * 8);
  };

  auto computeT = [&](int j0, const unsigned short* lK, const bf16x8 (&vr)[2][4]) {
    f32x4 sT[4] = {};
    __builtin_amdgcn_s_setprio(1);
#pragma unroll
    for (int n = 0; n < 4; ++n)
#pragma unroll
      for (int ks = 0; ks < 4; ++ks) {
        bf16x8 kf = *reinterpret_cast<const bf16x8*>(
            &lK[(n * 16 + (lane & 15)) * 128 + (((ks * 4 + (lane >> 4)) ^ swz)) * 8]);
        sT[n] = __builtin_amdgcn_mfma_f32_16x16x32_bf16(kf, qf[ks], sT[n], 0, 0, 0);
      }
    __builtin_amdgcn_s_setprio(0);

    if (j0 == q0) {  // diagonal tile: causal mask
#pragma unroll
      for (int n = 0; n < 4; ++n)
#pragma unroll
        for (int r = 0; r < 4; ++r) {
          int key = j0 + n * 16 + g * 4 + r;
          if (key > qa) sT[n][r] = -1e30f;
        }
    }

    // tree max over 16 values + 2 shfl
    float tm[4];
#pragma unroll
    for (int n = 0; n < 4; ++n)
      tm[n] = fmaxf(fmaxf(sT[n][0], sT[n][1]), fmaxf(sT[n][2], sT[n][3]));
    float mx = fmaxf(fmaxf(tm[0], tm[1]), fmaxf(tm[2], tm[3]));
    mx = fmaxf(mx, __shfl_xor(mx, 16));
    mx = fmaxf(mx, __shfl_xor(mx, 32));

    if (__any(mx - mrow > 8.0f)) {   // defer-max (T13), exp2 domain
      float mn = fmaxf(mrow, mx);
      float sf = exp2f(mrow - mn);
      mrow = mn;
      lrow *= sf;
      float sfr[4];
#pragma unroll
      for (int r = 0; r < 4; ++r) sfr[r] = __shfl(sf, (lane >> 4) * 4 + r);
#pragma unroll
      for (int n = 0; n < 4; ++n)
#pragma unroll
        for (int r = 0; r < 4; ++r) o_acc[n][r] *= sfr[r];
    }

    float psn[4];
    unsigned dw[4][2];
#pragma unroll
    for (int n = 0; n < 4; ++n) {
      float p0 = exp2f(sT[n][0] - mrow), p1 = exp2f(sT[n][1] - mrow);
      float p2 = exp2f(sT[n][2] - mrow), p3 = exp2f(sT[n][3] - mrow);
      psn[n] = (p0 + p1) + (p2 + p3);
      asm("v_cvt_pk_bf16_f32 %0, %1, %2" : "=v"(dw[n][0]) : "v"(p0), "v"(p1));
      asm("v_cvt_pk_bf16_f32 %0, %1, %2" : "=v"(dw[n][1]) : "v"(p2), "v"(p3));
    }
    float ps = (psn[0] + psn[1]) + (psn[2] + psn[3]);
    ps += __shfl_xor(ps, 16);
    ps += __shfl_xor(ps, 32);
    lrow += ps;

#pragma unroll
    for (int ks = 0; ks < 2; ++ks) {
      unsigned A0 = __shfl(dw[2 * ks][0], sl0);
      unsigned B0 = __shfl(dw[2 * ks + 1][0], sl0);
      unsigned A1 = __shfl(dw[2 * ks][1], sl0);
      unsigned B1 = __shfl(dw[2 * ks + 1][1], sl0);
      unsigned A2 = __shfl(dw[2 * ks][0], sl1);
      unsigned B2 = __shfl(dw[2 * ks + 1][0], sl1);
      unsigned A3 = __shfl(dw[2 * ks][1], sl1);
      unsigned B3 = __shfl(dw[2 * ks + 1][1], sl1);
      u32x4 mm;
      mm.x = hi ? B0 : A0; mm.y = hi ? B1 : A1;
      mm.z = hi ? B2 : A2; mm.w = hi ? B3 : A3;
      bf16x8 pa = __builtin_bit_cast(bf16x8, mm);
      __builtin_amdgcn_s_setprio(1);
#pragma unroll
      for (int n = 0; n < 4; ++n)
        o_acc[n] = __builtin_amdgcn_mfma_f32_16x16x32_bf16(pa, vr[ks][n], o_acc[n], 0, 0, 0);
      __builtin_amdgcn_s_setprio(0);
    }
  };

  // tiles t = j, j+2, ..., <= qb  (empty for qb=0,j=1: falls through)
  bf16x8 vr[2][4];
  unsigned short* cur = lK0;
  unsigned short* nxt = lK1;
  if (j <= qb) stage(j, cur);
  for (int t = j; t <= qb; t += 2) {
    __syncthreads();                         // cur ready (stage issued 1 compute ago)
    if (t + 2 <= qb) stage(t + 2, nxt);      // lands under computeT(t)
    loadV(t * 64, vr);                       // consumed at PV; hides under QK^T
    computeT(t * 64, cur, vr);
    unsigned short* tmp = cur; cur = nxt; nxt = tmp;
  }

  // partial epilogue: unnormalized O (f32) + (m,l) per q-row
  float* op = Op + (size_t)j * 4194304 + ((size_t)h * 2048 + firstrow) * 64;
#pragma unroll
  for (int n = 0; n < 4; ++n)
#pragma unroll
    for (int r = 0; r < 4; ++r)
      op[(size_t)(g * 4 + r) * 64 + n * 16 + (lane & 15)] = o_acc[n][r];
  if (lane < 16)
    Ml[(size_t)j * 65536 + h * 2048 + qa] = make_float2(mrow, lrow);
}

// ---------------- flash combine: LSE-merge the two partials -----------------
__global__ __launch_bounds__(256) void flash_combine(const float* __restrict__ Op,
                                                     const float2* __restrict__ Ml,
                                                     unsigned short* __restrict__ Ao) {
  size_t i4 = ((size_t)blockIdx.x * 256 + threadIdx.x) * 4;  // over 2048*2048
  int s = (int)(i4 >> 11);
  int c = (int)(i4 & 2047);
  int h = c >> 6, d = c & 63;
  float2 a = Ml[h * 2048 + s];
  float2 b = Ml[65536 + h * 2048 + s];
  float M = fmaxf(a.x, b.x);
  float w0 = exp2f(a.x - M), w1 = exp2f(b.x - M);
  float inv = 1.f / (w0 * a.y + w1 * b.y);
  size_t pidx = ((size_t)h * 2048 + s) * 64 + d;
  float4 o0 = *reinterpret_cast<const float4*>(Op + pidx);
  float4 o1 = *reinterpret_cast<const float4*>(Op + 4194304 + pidx);
  *reinterpret_cast<ushort4*>(Ao + (size_t)s * 2048 + h * 64 + d) =
      make_ushort4(f2bf((w0 * o0.x + w1 * o1.x) * inv),
                   f2bf((w0 * o0.y + w1 * o1.y) * inv),
                   f2bf((w0 * o0.z + w1 * o1.z) * inv),
                   f2bf((w0 * o0.w + w1 * o1.w) * inv));
}

// ---------------------------------------------------------------------------
extern "C" void kernel_launch(void* const* d_in, const int* in_sizes, int n_in,
                              void* d_out, int out_size, void* d_ws, size_t ws_size,
                              hipStream_t stream) {
  const float* hs   = (const float*)d_in[0];
  const float* cosp = (const float*)d_in[1];
  const float* sinp = (const float*)d_in[2];
  const float* qaw  = (const float*)d_in[3];
  const float* qaln = (const float*)d_in[4];
  const float* qbwf = (const float*)d_in[5];
  const float* kvaw = (const float*)d_in[6];
  const float* kvln = (const float*)d_in[7];
  const float* kvbwf= (const float*)d_in[8];
  const float* owf  = (const float*)d_in[9];
  float* out = (float*)d_out;
  char* ws = (char*)d_ws;
  const size_t MB = 1u << 20;

  // overlay map (lifetimes):
  unsigned short* W1b  = (unsigned short*)(ws + 0);        // 8 MB   [dead after gemm1]
  unsigned short* Ao   = (unsigned short*)(ws + 0);        // 8 MB   (combine out)
  unsigned short* qbw  = (unsigned short*)(ws + 8 * MB);   // 8 MB   [dead after gemm2]
  unsigned short* Vt   = (unsigned short*)(ws + 8 * MB);   // 8 MB   (kv_post out)
  unsigned short* kvbw = (unsigned short*)(ws + 16 * MB);  // 7 MB   [dead after gemm2]
  unsigned short* owb  = (unsigned short*)(ws + 23 * MB);  // 8 MB
  unsigned short* hsb  = (unsigned short*)(ws + 31 * MB);  // 8 MB   [dead after gemm1]
  unsigned short* Qfb  = (unsigned short*)(ws + 31 * MB);  // 16 MB  (gemm2 out, raw Q bf16)
  float*          C1   = (float*)(ws + 47 * MB);           // 16 MB  [dead after rmsnorm]
  unsigned short* KVfb = (unsigned short*)(ws + 63 * MB);  // 16 MB  (gemm2 out bf16)
  unsigned short* kr   = (unsigned short*)(ws + 79 * MB);  // 0.25 MB
  unsigned short* qln  = (unsigned short*)(ws + 80 * MB);  // 4 MB   [dead after gemm2]
  unsigned short* ckvn = (unsigned short*)(ws + 84 * MB);  // 3.5 MB [dead after gemm2]
  float*          Op   = (float*)(ws + 88 * MB);           // 2x16.78 MB (flash partials)
  float2*         Mlp  = (float2*)(ws + 122 * MB);         // 2x0.5 MB
  (void)ws_size; (void)in_sizes; (void)n_in; (void)out_size;

  // ---- one fused convert launch (6 segments) ----
  CvtSegs sg;
  sg.src[0] = qaw;   sg.dst[0] = W1b;                      sg.n_src[0] = 1024u * 2048u; sg.n_tot[0] = 1024u * 2048u;
  sg.src[1] = kvaw;  sg.dst[1] = W1b + (size_t)1024 * 2048; sg.n_src[1] = 960u * 2048u;  sg.n_tot[1] = 1024u * 2048u;
  sg.src[2] = hs;    sg.dst[2] = hsb;                      sg.n_src[2] = 2048u * 2048u; sg.n_tot[2] = 2048u * 2048u;
  sg.src[3] = qbwf;  sg.dst[3] = qbw;                      sg.n_src[3] = 4096u * 1024u; sg.n_tot[3] = 4096u * 1024u;
  sg.src[4] = kvbwf; sg.dst[4] = kvbw;                     sg.n_src[4] = 4096u * 896u;  sg.n_tot[4] = 4096u * 896u;
  sg.src[5] = owf;   sg.dst[5] = owb;                      sg.n_src[5] = 2048u * 2048u; sg.n_tot[5] = 2048u * 2048u;
  sg.blk0[0] = 0;
  for (int k = 0; k < 6; ++k) sg.blk0[k + 1] = sg.blk0[k] + sg.n_tot[k] / 1024u;
  cvt_all<<<dim3(sg.blk0[6]), 256, 0, stream>>>(sg);

  gemm_bt2<float><<<dim3(32, 16), 512, 0, stream>>>(hsb, W1b, C1, 2048, 2048, 2048);
  rmsnorm_rope<<<2048, 256, 0, stream>>>(C1, qaln, kvln, cosp, sinp, qln, ckvn, kr);

  // grouped: Qfb = qln @ qbw^T  and  KVfb = ckvn @ kvbw^T  in one launch
  gemm_bt2_pair<<<dim3(2048), 512, 0, stream>>>(qln, qbw, Qfb, 1024,
                                                ckvn, kvbw, KVfb, 896);

  kv_post<<<dim3(32, 32), 256, 0, stream>>>(KVfb, Vt);

  flash_attn<<<dim3(32, 64), 256, 0, stream>>>(Qfb, KVfb, kr, cosp, sinp, Vt, Op, Mlp);
  flash_combine<<<dim3(4096), 256, 0, stream>>>(Op, Mlp, Ao);

  gemm_bt2<float><<<dim3(32, 16), 512, 0, stream>>>(Ao, owb, out, 2048, 2048, 2048);
}

// Round 15
// 212.407 us; speedup vs baseline: 1.2832x; 1.0174x over previous
//
#include <hip/hip_runtime.h>

// ---------------------------------------------------------------------------
// MLA (LoraQKV) pipeline for MI355X, bf16 MFMA everywhere.
//   1) cvt_all; 2) gemm C1 = hs@W1^T (bf16); 3) rmsnorm_rope;
//   4) grouped gemm Qfb+KVfb (bf16, one launch); 5) kv_post (V^T);
//   6) flash_attn (Q-RoPE fused, K from KVfb+kr, 2-way key-split, bf16
//      partials) + combine; 7) gemm out = Ao@o_w^T (f32).
// R15: dtype-only traffic cuts. C1 bf16 (gemm1 write + rmsnorm read halved);
//     flash partial O bf16 (Op write + combine read halved). ~40MB less HBM.
//     No sync-structure changes (R7/R8/R9/R13 lesson).
// ---------------------------------------------------------------------------

typedef __attribute__((ext_vector_type(8))) __bf16 bf16x8;
typedef __attribute__((ext_vector_type(4))) float f32x4;
typedef __attribute__((ext_vector_type(4))) unsigned u32x4;

__device__ __forceinline__ unsigned short f2bf(float f) {
  unsigned int x = __builtin_bit_cast(unsigned int, f);
  x += 0x7fffu + ((x >> 16) & 1u);
  return (unsigned short)(x >> 16);
}
__device__ __forceinline__ float bf2f(unsigned short u) {
  unsigned int x = ((unsigned int)u) << 16;
  return __builtin_bit_cast(float, x);
}
__device__ __forceinline__ void gload_lds16(const void* g, void* l) {
  __builtin_amdgcn_global_load_lds(
      (const __attribute__((address_space(1))) void*)g,
      (__attribute__((address_space(3))) void*)l, 16, 0, 0);
}
__device__ __forceinline__ void cstore(float* C, size_t i, float v) { C[i] = v; }
__device__ __forceinline__ void cstore(unsigned short* C, size_t i, float v) { C[i] = f2bf(v); }

// ---------------- segmented convert (all f32->bf16 converts in one launch) --
struct CvtSegs {
  const float* src[6];
  unsigned short* dst[6];
  unsigned int n_src[6];
  unsigned int n_tot[6];
  unsigned int blk0[7];
};

__global__ __launch_bounds__(256) void cvt_all(CvtSegs sg) {
  int b = blockIdx.x;
  int seg = 0;
#pragma unroll
  for (int k = 0; k < 5; ++k)
    if (b >= (int)sg.blk0[k + 1]) seg = k + 1;
  size_t i = ((size_t)(b - sg.blk0[seg]) * 256 + threadIdx.x) * 4;
  if (i >= sg.n_tot[seg]) return;
  unsigned short o0 = 0, o1 = 0, o2 = 0, o3 = 0;
  if (i < sg.n_src[seg]) {
    float4 v = *reinterpret_cast<const float4*>(sg.src[seg] + i);
    o0 = f2bf(v.x); o1 = f2bf(v.y); o2 = f2bf(v.z); o3 = f2bf(v.w);
  }
  *reinterpret_cast<ushort4*>(sg.dst[seg] + i) = make_ushort4(o0, o1, o2, o3);
}

// ---------------- GEMM core (shared by single and grouped kernels) ----------
// 128x64 tile, BK=64, 512 threads (8 waves 4x2, wave tile 32x32), dbuf LDS,
// 2-phase; T2 swizzle via pre-swizzled gload source.
template <typename OutT>
__device__ __forceinline__ void gemm_body(const unsigned short* __restrict__ A,
                                          const unsigned short* __restrict__ B,
                                          OutT* __restrict__ C,
                                          int N, int K, int bm, int bn,
                                          unsigned short* lA0, unsigned short* lA1,
                                          unsigned short* lB0, unsigned short* lB1) {
  const int tid = threadIdx.x, lane = tid & 63, wv = tid >> 6;
  const int wr = wv >> 1, wc = wv & 1;             // 4x2 wave grid

  f32x4 acc[2][2] = {};

  const int ar0 = tid >> 3;
  const int acol = (((tid & 7) ^ ((tid >> 3) & 7))) * 8;   // T2 pre-swizzled src
  const int swz = lane & 7;

  auto stage = [&](unsigned short* la, unsigned short* lb, int k0) {
#pragma unroll
    for (int i = 0; i < 2; ++i)
      gload_lds16(A + (size_t)(bm + i * 64 + ar0) * K + k0 + acol,
                  &la[(i * 512 + wv * 64) * 8]);
    gload_lds16(B + (size_t)(bn + ar0) * K + k0 + acol, &lb[(wv * 64) * 8]);
  };

  auto compute = [&](const unsigned short* la, const unsigned short* lb) {
#pragma unroll
    for (int ks = 0; ks < 2; ++ks) {
      const int ch = ((ks * 4 + (lane >> 4)) ^ swz) * 8;
      bf16x8 af[2], bfr[2];
#pragma unroll
      for (int m = 0; m < 2; ++m)
        af[m] = *reinterpret_cast<const bf16x8*>(
            &la[(wr * 32 + m * 16 + (lane & 15)) * 64 + ch]);
#pragma unroll
      for (int n = 0; n < 2; ++n)
        bfr[n] = *reinterpret_cast<const bf16x8*>(
            &lb[(wc * 32 + n * 16 + (lane & 15)) * 64 + ch]);
      __builtin_amdgcn_s_setprio(1);
#pragma unroll
      for (int m = 0; m < 2; ++m)
#pragma unroll
        for (int n = 0; n < 2; ++n)
          acc[m][n] = __builtin_amdgcn_mfma_f32_16x16x32_bf16(af[m], bfr[n], acc[m][n], 0, 0, 0);
      __builtin_amdgcn_s_setprio(0);
    }
  };

  stage(lA0, lB0, 0);
  for (int k0 = 0; k0 < K; k0 += 128) {   // K % 128 == 0 for all call sites
    __syncthreads();                      // stage(k0) -> buf0 ready
    stage(lA1, lB1, k0 + 64);             // in flight during compute(buf0)
    compute(lA0, lB0);
    __syncthreads();                      // buf1 ready (hidden); buf0 free
    if (k0 + 128 < K) stage(lA0, lB0, k0 + 128);
    compute(lA1, lB1);
  }

  const int r0 = bm + wr * 32, c0 = bn + wc * 32;
#pragma unroll
  for (int m = 0; m < 2; ++m)
#pragma unroll
    for (int n = 0; n < 2; ++n)
#pragma unroll
      for (int r = 0; r < 4; ++r)
        cstore(C, (size_t)(r0 + m * 16 + (lane >> 4) * 4 + r) * N + c0 + n * 16 + (lane & 15),
               acc[m][n][r]);
}

template <typename OutT>
__global__ __launch_bounds__(512, 4) void gemm_bt2(const unsigned short* __restrict__ A,
                                                   const unsigned short* __restrict__ B,
                                                   OutT* __restrict__ C,
                                                   int M, int N, int K) {
  __shared__ unsigned short lA0[128 * 64], lA1[128 * 64];
  __shared__ unsigned short lB0[64 * 64], lB1[64 * 64];
  // T1: XCD-aware block swizzle (nwg % 8 == 0 at every call site)
  unsigned nwg = gridDim.x * gridDim.y;
  unsigned lid = blockIdx.y * gridDim.x + blockIdx.x;
  unsigned swz_id = (lid & 7) * (nwg >> 3) + (lid >> 3);
  const int bm = (int)(swz_id / gridDim.x) * 128;
  const int bn = (int)(swz_id % gridDim.x) * 64;
  gemm_body<OutT>(A, B, C, N, K, bm, bn, lA0, lA1, lB0, lB1);
}

// grouped: blocks [0,1024) -> problem 0 (K0), [1024,2048) -> problem 1 (K1).
// Both M=2048, N=4096 (16 x 64 tile grid per problem).
__global__ __launch_bounds__(512, 4) void gemm_bt2_pair(const unsigned short* __restrict__ A0,
                                                        const unsigned short* __restrict__ B0,
                                                        unsigned short* __restrict__ C0,
                                                        int K0,
                                                        const unsigned short* __restrict__ A1,
                                                        const unsigned short* __restrict__ B1,
                                                        unsigned short* __restrict__ C1,
                                                        int K1) {
  __shared__ unsigned short lA0[128 * 64], lA1[128 * 64];
  __shared__ unsigned short lB0[64 * 64], lB1[64 * 64];
  const int p = blockIdx.x >= 1024;
  unsigned lid = blockIdx.x & 1023;
  unsigned swz_id = (lid & 7) * 128 + (lid >> 3);       // T1 within the half
  const int bm = (int)(swz_id >> 6) * 128;
  const int bn = (int)(swz_id & 63) * 64;
  if (!p)
    gemm_body<unsigned short>(A0, B0, C0, 4096, K0, bm, bn, lA0, lA1, lB0, lB1);
  else
    gemm_body<unsigned short>(A1, B1, C1, 4096, K1, bm, bn, lA0, lA1, lB0, lB1);
}

// ---------------- RMSNorm(q_lat), RMSNorm(c_kv), RoPE(k_rope) ---------------
// C1 is bf16 now (stats still accumulated in f32).
__global__ __launch_bounds__(256) void rmsnorm_rope(const unsigned short* __restrict__ C1,
                                                    const float* __restrict__ qw,
                                                    const float* __restrict__ kvw,
                                                    const float* __restrict__ cosp,
                                                    const float* __restrict__ sinp,
                                                    unsigned short* __restrict__ qn,
                                                    unsigned short* __restrict__ ckvn,
                                                    unsigned short* __restrict__ kr) {
  const int s = blockIdx.x, tid = threadIdx.x;
  const unsigned short* row = C1 + (size_t)s * 2048;
  __shared__ float red[4];

  ushort4 v4 = *reinterpret_cast<const ushort4*>(row + tid * 4);
  float vx = bf2f(v4.x), vy = bf2f(v4.y), vz = bf2f(v4.z), vw = bf2f(v4.w);
  float ss = vx * vx + vy * vy + vz * vz + vw * vw;
  ss += __shfl_xor(ss, 32); ss += __shfl_xor(ss, 16); ss += __shfl_xor(ss, 8);
  ss += __shfl_xor(ss, 4);  ss += __shfl_xor(ss, 2);  ss += __shfl_xor(ss, 1);
  if ((tid & 63) == 0) red[tid >> 6] = ss;
  __syncthreads();
  float rs = rsqrtf((red[0] + red[1] + red[2] + red[3]) * (1.f / 1024.f) + 1e-6f);
  {
    float4 w = *reinterpret_cast<const float4*>(qw + tid * 4);
    *reinterpret_cast<ushort4*>(qn + (size_t)s * 1024 + tid * 4) =
        make_ushort4(f2bf(vx * rs * w.x), f2bf(vy * rs * w.y),
                     f2bf(vz * rs * w.z), f2bf(vw * rs * w.w));
  }

  float ux = 0.f, uy = 0.f, uz = 0.f, uw = 0.f;
  if (tid < 224) {
    ushort4 u4 = *reinterpret_cast<const ushort4*>(row + 1024 + tid * 4);
    ux = bf2f(u4.x); uy = bf2f(u4.y); uz = bf2f(u4.z); uw = bf2f(u4.w);
  }
  ss = ux * ux + uy * uy + uz * uz + uw * uw;
  ss += __shfl_xor(ss, 32); ss += __shfl_xor(ss, 16); ss += __shfl_xor(ss, 8);
  ss += __shfl_xor(ss, 4);  ss += __shfl_xor(ss, 2);  ss += __shfl_xor(ss, 1);
  __syncthreads();
  if ((tid & 63) == 0) red[tid >> 6] = ss;
  __syncthreads();
  rs = rsqrtf((red[0] + red[1] + red[2] + red[3]) * (1.f / 896.f) + 1e-6f);
  if (tid < 224) {
    float4 w = *reinterpret_cast<const float4*>(kvw + tid * 4);
    *reinterpret_cast<ushort4*>(ckvn + (size_t)s * 896 + tid * 4) =
        make_ushort4(f2bf(ux * rs * w.x), f2bf(uy * rs * w.y),
                     f2bf(uz * rs * w.z), f2bf(uw * rs * w.w));
  }

  if (tid < 64) {
    int d = tid;
    float x = bf2f(row[1920 + d]);
    float part = (d < 32) ? -bf2f(row[1920 + d + 32]) : bf2f(row[1920 + d - 32]);
    float vv = x * cosp[(size_t)s * 64 + d] + part * sinp[(size_t)s * 64 + d];
    kr[(size_t)s * 64 + d] = f2bf(vv);
  }
}

// ---------------- KV post: Vt = V^T (pure bf16 transpose) -------------------
__global__ __launch_bounds__(256) void kv_post(const unsigned short* __restrict__ KVfb,
                                               unsigned short* __restrict__ Vt) {
  __shared__ unsigned short lT[64 * 65];
  const int s0 = blockIdx.x * 64, h = blockIdx.y, tid = threadIdx.x;
  for (int idx = tid; idx < 4096; idx += 256) {
    int r = idx >> 6, c = idx & 63;
    lT[r * 65 + c] = KVfb[(size_t)(s0 + r) * 4096 + h * 128 + 64 + c];
  }
  __syncthreads();
  for (int idx = tid; idx < 4096; idx += 256) {
    int d = idx >> 6, c = idx & 63;
    Vt[((size_t)h * 64 + d) * 2048 + s0 + c] = lT[c * 65 + d];
  }
}

// ---------------- flash attention (causal, 2-way key-split partials) --------
// grid (32 heads, 64): qb = 31-(y>>1) (LPT), j = y&1; tiles t%2==j, t<=qb.
// 4 blocks/CU (VGPR 64, no spill). Q-load fused RoPE+SCALE*log2e; K staged
// straight from KVfb (nope) + kr (rope). Partial O now bf16 (traffic halved);
// per-row (m,l) stays f32.
__global__ __launch_bounds__(256, 4) void flash_attn(const unsigned short* __restrict__ Qfb,
                                                     const unsigned short* __restrict__ KVfb,
                                                     const unsigned short* __restrict__ kr,
                                                     const float* __restrict__ cosp,
                                                     const float* __restrict__ sinp,
                                                     const unsigned short* __restrict__ Vt,
                                                     unsigned short* __restrict__ Op,
                                                     float2* __restrict__ Ml) {
  __shared__ unsigned short lK0[64 * 128], lK1[64 * 128];
  const int tid = threadIdx.x, lane = tid & 63, wv = tid >> 6;
  const int h = blockIdx.x;
  const int qb = 31 - ((int)blockIdx.y >> 1);            // LPT: heavy first
  const int j = (int)blockIdx.y & 1;                     // key-split half
  const int q0 = qb * 64;
  const int firstrow = q0 + wv * 16;
  const int g = lane >> 4;
  const int qa = firstrow + (lane & 15);                 // this lane's q-row
  const float SC = 0.18033688f;                          // 0.125 * log2(e)

  // ---- Q load + fused RoPE + scale (once per block) ----
  bf16x8 qf[4];
  {
    const unsigned short* qr = Qfb + (size_t)qa * 4096 + h * 128;
    float raw[4][8];
#pragma unroll
    for (int ks = 0; ks < 4; ++ks) {
      ushort4 u0 = *reinterpret_cast<const ushort4*>(qr + ks * 32 + g * 8);
      ushort4 u1 = *reinterpret_cast<const ushort4*>(qr + ks * 32 + g * 8 + 4);
      raw[ks][0] = bf2f(u0.x); raw[ks][1] = bf2f(u0.y);
      raw[ks][2] = bf2f(u0.z); raw[ks][3] = bf2f(u0.w);
      raw[ks][4] = bf2f(u1.x); raw[ks][5] = bf2f(u1.y);
      raw[ks][6] = bf2f(u1.z); raw[ks][7] = bf2f(u1.w);
    }
    const float* cp = cosp + (size_t)qa * 64 + g * 8;
    const float* sp = sinp + (size_t)qa * 64 + g * 8;
    float c0[8], s0[8], c1[8], s1[8];
    {
      float4 a = *reinterpret_cast<const float4*>(cp);
      float4 b = *reinterpret_cast<const float4*>(cp + 4);
      c0[0]=a.x;c0[1]=a.y;c0[2]=a.z;c0[3]=a.w;c0[4]=b.x;c0[5]=b.y;c0[6]=b.z;c0[7]=b.w;
      a = *reinterpret_cast<const float4*>(cp + 32);
      b = *reinterpret_cast<const float4*>(cp + 36);
      c1[0]=a.x;c1[1]=a.y;c1[2]=a.z;c1[3]=a.w;c1[4]=b.x;c1[5]=b.y;c1[6]=b.z;c1[7]=b.w;
      a = *reinterpret_cast<const float4*>(sp);
      b = *reinterpret_cast<const float4*>(sp + 4);
      s0[0]=a.x;s0[1]=a.y;s0[2]=a.z;s0[3]=a.w;s0[4]=b.x;s0[5]=b.y;s0[6]=b.z;s0[7]=b.w;
      a = *reinterpret_cast<const float4*>(sp + 32);
      b = *reinterpret_cast<const float4*>(sp + 36);
      s1[0]=a.x;s1[1]=a.y;s1[2]=a.z;s1[3]=a.w;s1[4]=b.x;s1[5]=b.y;s1[6]=b.z;s1[7]=b.w;
    }
    alignas(16) unsigned short pk[4][8];
#pragma unroll
    for (int e = 0; e < 8; ++e) {
      pk[0][e] = f2bf(raw[0][e] * SC);
      pk[1][e] = f2bf(raw[1][e] * SC);
      pk[2][e] = f2bf((raw[2][e] * c0[e] - raw[3][e] * s0[e]) * SC);
      pk[3][e] = f2bf((raw[3][e] * c1[e] + raw[2][e] * s1[e]) * SC);
    }
#pragma unroll
    for (int ks = 0; ks < 4; ++ks)
      qf[ks] = *reinterpret_cast<const bf16x8*>(pk[ks]);
  }

  f32x4 o_acc[4] = {};
  float mrow = -1e30f, lrow = 0.f;   // per-lane: stats of q-row qa

  const int sl0 = ((g & 1) * 2) * 16 + (lane & 15);   // src lane, m=0,1
  const int sl1 = sl0 + 16;                           // src lane, m=2,3
  const bool hi = g >= 2;                             // selects src_n = 2ks+1

  const int krow = wv * 4 + (lane >> 4);
  const int cs = (lane & 15) ^ (krow & 7);            // swizzled source chunk
  const int swz = lane & 7;                           // read-side row&7

  auto stage = [&](int t, unsigned short* lK) {
    int jj = t * 64;
#pragma unroll
    for (int i = 0; i < 4; ++i) {
      int s = jj + i * 16 + krow;
      const unsigned short* src =
          (cs < 8) ? KVfb + (size_t)s * 4096 + h * 128 + cs * 8
                   : kr + (size_t)s * 64 + (cs - 8) * 8;
      gload_lds16(src, &lK[(i * 16 + wv * 4) * 128]);
    }
  };

  auto loadV = [&](int j0, bf16x8 (&vr)[2][4]) {
#pragma unroll
    for (int ks = 0; ks < 2; ++ks)
#pragma unroll
      for (int n = 0; n < 4; ++n)
        vr[ks][n] = *reinterpret_cast<const bf16x8*>(
            Vt + ((size_t)h * 64 + n * 16 + (lane & 15)) * 2048 + j0 + ks * 32 +
            (lane >> 4) * 8);
  };

  auto computeT = [&](int j0, const unsigned short* lK, const bf16x8 (&vr)[2][4]) {
    f32x4 sT[4] = {};
    __builtin_amdgcn_s_setprio(1);
#pragma unroll
    for (int n = 0; n < 4; ++n)
#pragma unroll
      for (int ks = 0; ks < 4; ++ks) {
        bf16x8 kf = *reinterpret_cast<const bf16x8*>(
            &lK[(n * 16 + (lane & 15)) * 128 + (((ks * 4 + (lane >> 4)) ^ swz)) * 8]);
        sT[n] = __builtin_amdgcn_mfma_f32_16x16x32_bf16(kf, qf[ks], sT[n], 0, 0, 0);
      }
    __builtin_amdgcn_s_setprio(0);

    if (j0 == q0) {  // diagonal tile: causal mask
#pragma unroll
      for (int n = 0; n < 4; ++n)
#pragma unroll
        for (int r = 0; r < 4; ++r) {
          int key = j0 + n * 16 + g * 4 + r;
          if (key > qa) sT[n][r] = -1e30f;
        }
    }

    // tree max over 16 values + 2 shfl
    float tm[4];
#pragma unroll
    for (int n = 0; n < 4; ++n)
      tm[n] = fmaxf(fmaxf(sT[n][0], sT[n][1]), fmaxf(sT[n][2], sT[n][3]));
    float mx = fmaxf(fmaxf(tm[0], tm[1]), fmaxf(tm[2], tm[3]));
    mx = fmaxf(mx, __shfl_xor(mx, 16));
    mx = fmaxf(mx, __shfl_xor(mx, 32));

    if (__any(mx - mrow > 8.0f)) {   // defer-max (T13), exp2 domain
      float mn = fmaxf(mrow, mx);
      float sf = exp2f(mrow - mn);
      mrow = mn;
      lrow *= sf;
      float sfr[4];
#pragma unroll
      for (int r = 0; r < 4; ++r) sfr[r] = __shfl(sf, (lane >> 4) * 4 + r);
#pragma unroll
      for (int n = 0; n < 4; ++n)
#pragma unroll
        for (int r = 0; r < 4; ++r) o_acc[n][r] *= sfr[r];
    }

    float psn[4];
    unsigned dw[4][2];
#pragma unroll
    for (int n = 0; n < 4; ++n) {
      float p0 = exp2f(sT[n][0] - mrow), p1 = exp2f(sT[n][1] - mrow);
      float p2 = exp2f(sT[n][2] - mrow), p3 = exp2f(sT[n][3] - mrow);
      psn[n] = (p0 + p1) + (p2 + p3);
      asm("v_cvt_pk_bf16_f32 %0, %1, %2" : "=v"(dw[n][0]) : "v"(p0), "v"(p1));
      asm("v_cvt_pk_bf16_f32 %0, %1, %2" : "=v"(dw[n][1]) : "v"(p2), "v"(p3));
    }
    float ps = (psn[0] + psn[1]) + (psn[2] + psn[3]);
    ps += __shfl_xor(ps, 16);
    ps += __shfl_xor(ps, 32);
    lrow += ps;

#pragma unroll
    for (int ks = 0; ks < 2; ++ks) {
      unsigned A0 = __shfl(dw[2 * ks][0], sl0);
      unsigned B0 = __shfl(dw[2 * ks + 1][0], sl0);
      unsigned A1 = __shfl(dw[2 * ks][1], sl0);
      unsigned B1 = __shfl(dw[2 * ks + 1][1], sl0);
      unsigned A2 = __shfl(dw[2 * ks][0], sl1);
      unsigned B2 = __shfl(dw[2 * ks + 1][0], sl1);
      unsigned A3 = __shfl(dw[2 * ks][1], sl1);
      unsigned B3 = __shfl(dw[2 * ks + 1][1], sl1);
      u32x4 mm;
      mm.x = hi ? B0 : A0; mm.y = hi ? B1 : A1;
      mm.z = hi ? B2 : A2; mm.w = hi ? B3 : A3;
      bf16x8 pa = __builtin_bit_cast(bf16x8, mm);
      __builtin_amdgcn_s_setprio(1);
#pragma unroll
      for (int n = 0; n < 4; ++n)
        o_acc[n] = __builtin_amdgcn_mfma_f32_16x16x32_bf16(pa, vr[ks][n], o_acc[n], 0, 0, 0);
      __builtin_amdgcn_s_setprio(0);
    }
  };

  // tiles t = j, j+2, ..., <= qb  (empty for qb=0,j=1: falls through)
  bf16x8 vr[2][4];
  unsigned short* cur = lK0;
  unsigned short* nxt = lK1;
  if (j <= qb) stage(j, cur);
  for (int t = j; t <= qb; t += 2) {
    __syncthreads();                         // cur ready (stage issued 1 compute ago)
    if (t + 2 <= qb) stage(t + 2, nxt);      // lands under computeT(t)
    loadV(t * 64, vr);                       // consumed at PV; hides under QK^T
    computeT(t * 64, cur, vr);
    unsigned short* tmp = cur; cur = nxt; nxt = tmp;
  }

  // partial epilogue: unnormalized O (bf16) + (m,l) per q-row (f32)
  unsigned short* op = Op + (size_t)j * 4194304 + ((size_t)h * 2048 + firstrow) * 64;
#pragma unroll
  for (int n = 0; n < 4; ++n)
#pragma unroll
    for (int r = 0; r < 4; ++r)
      op[(size_t)(g * 4 + r) * 64 + n * 16 + (lane & 15)] = f2bf(o_acc[n][r]);
  if (lane < 16)
    Ml[(size_t)j * 65536 + h * 2048 + qa] = make_float2(mrow, lrow);
}

// ---------------- flash combine: LSE-merge the two partials -----------------
__global__ __launch_bounds__(256) void flash_combine(const unsigned short* __restrict__ Op,
                                                     const float2* __restrict__ Ml,
                                                     unsigned short* __restrict__ Ao) {
  size_t i4 = ((size_t)blockIdx.x * 256 + threadIdx.x) * 4;  // over 2048*2048
  int s = (int)(i4 >> 11);
  int c = (int)(i4 & 2047);
  int h = c >> 6, d = c & 63;
  float2 a = Ml[h * 2048 + s];
  float2 b = Ml[65536 + h * 2048 + s];
  float M = fmaxf(a.x, b.x);
  float w0 = exp2f(a.x - M), w1 = exp2f(b.x - M);
  float inv = 1.f / (w0 * a.y + w1 * b.y);
  size_t pidx = ((size_t)h * 2048 + s) * 64 + d;
  ushort4 p0 = *reinterpret_cast<const ushort4*>(Op + pidx);
  ushort4 p1 = *reinterpret_cast<const ushort4*>(Op + 4194304 + pidx);
  *reinterpret_cast<ushort4*>(Ao + (size_t)s * 2048 + h * 64 + d) =
      make_ushort4(f2bf((w0 * bf2f(p0.x) + w1 * bf2f(p1.x)) * inv),
                   f2bf((w0 * bf2f(p0.y) + w1 * bf2f(p1.y)) * inv),
                   f2bf((w0 * bf2f(p0.z) + w1 * bf2f(p1.z)) * inv),
                   f2bf((w0 * bf2f(p0.w) + w1 * bf2f(p1.w)) * inv));
}

// ---------------------------------------------------------------------------
extern "C" void kernel_launch(void* const* d_in, const int* in_sizes, int n_in,
                              void* d_out, int out_size, void* d_ws, size_t ws_size,
                              hipStream_t stream) {
  const float* hs   = (const float*)d_in[0];
  const float* cosp = (const float*)d_in[1];
  const float* sinp = (const float*)d_in[2];
  const float* qaw  = (const float*)d_in[3];
  const float* qaln = (const float*)d_in[4];
  const float* qbwf = (const float*)d_in[5];
  const float* kvaw = (const float*)d_in[6];
  const float* kvln = (const float*)d_in[7];
  const float* kvbwf= (const float*)d_in[8];
  const float* owf  = (const float*)d_in[9];
  float* out = (float*)d_out;
  char* ws = (char*)d_ws;
  const size_t MB = 1u << 20;

  // overlay map (lifetimes):
  unsigned short* W1b  = (unsigned short*)(ws + 0);        // 8 MB   [dead after gemm1]
  unsigned short* Ao   = (unsigned short*)(ws + 0);        // 8 MB   (combine out)
  unsigned short* qbw  = (unsigned short*)(ws + 8 * MB);   // 8 MB   [dead after gemm2]
  unsigned short* Vt   = (unsigned short*)(ws + 8 * MB);   // 8 MB   (kv_post out)
  unsigned short* kvbw = (unsigned short*)(ws + 16 * MB);  // 7 MB   [dead after gemm2]
  unsigned short* owb  = (unsigned short*)(ws + 23 * MB);  // 8 MB
  unsigned short* hsb  = (unsigned short*)(ws + 31 * MB);  // 8 MB   [dead after gemm1]
  unsigned short* Qfb  = (unsigned short*)(ws + 31 * MB);  // 16 MB  (gemm2 out, raw Q bf16)
  unsigned short* C1b  = (unsigned short*)(ws + 47 * MB);  // 8 MB   [dead after rmsnorm]
  unsigned short* KVfb = (unsigned short*)(ws + 63 * MB);  // 16 MB  (gemm2 out bf16)
  unsigned short* kr   = (unsigned short*)(ws + 79 * MB);  // 0.25 MB
  unsigned short* qln  = (unsigned short*)(ws + 80 * MB);  // 4 MB   [dead after gemm2]
  unsigned short* ckvn = (unsigned short*)(ws + 84 * MB);  // 3.5 MB [dead after gemm2]
  unsigned short* Op   = (unsigned short*)(ws + 88 * MB);  // 2x8.39 MB (flash partials, bf16)
  float2*         Mlp  = (float2*)(ws + 106 * MB);         // 2x0.5 MB
  (void)ws_size; (void)in_sizes; (void)n_in; (void)out_size;

  // ---- one fused convert launch (6 segments) ----
  CvtSegs sg;
  sg.src[0] = qaw;   sg.dst[0] = W1b;                      sg.n_src[0] = 1024u * 2048u; sg.n_tot[0] = 1024u * 2048u;
  sg.src[1] = kvaw;  sg.dst[1] = W1b + (size_t)1024 * 2048; sg.n_src[1] = 960u * 2048u;  sg.n_tot[1] = 1024u * 2048u;
  sg.src[2] = hs;    sg.dst[2] = hsb;                      sg.n_src[2] = 2048u * 2048u; sg.n_tot[2] = 2048u * 2048u;
  sg.src[3] = qbwf;  sg.dst[3] = qbw;                      sg.n_src[3] = 4096u * 1024u; sg.n_tot[3] = 4096u * 1024u;
  sg.src[4] = kvbwf; sg.dst[4] = kvbw;                     sg.n_src[4] = 4096u * 896u;  sg.n_tot[4] = 4096u * 896u;
  sg.src[5] = owf;   sg.dst[5] = owb;                      sg.n_src[5] = 2048u * 2048u; sg.n_tot[5] = 2048u * 2048u;
  sg.blk0[0] = 0;
  for (int k = 0; k < 6; ++k) sg.blk0[k + 1] = sg.blk0[k] + sg.n_tot[k] / 1024u;
  cvt_all<<<dim3(sg.blk0[6]), 256, 0, stream>>>(sg);

  gemm_bt2<unsigned short><<<dim3(32, 16), 512, 0, stream>>>(hsb, W1b, C1b, 2048, 2048, 2048);
  rmsnorm_rope<<<2048, 256, 0, stream>>>(C1b, qaln, kvln, cosp, sinp, qln, ckvn, kr);

  // grouped: Qfb = qln @ qbw^T  and  KVfb = ckvn @ kvbw^T  in one launch
  gemm_bt2_pair<<<dim3(2048), 512, 0, stream>>>(qln, qbw, Qfb, 1024,
                                                ckvn, kvbw, KVfb, 896);

  kv_post<<<dim3(32, 32), 256, 0, stream>>>(KVfb, Vt);

  flash_attn<<<dim3(32, 64), 256, 0, stream>>>(Qfb, KVfb, kr, cosp, sinp, Vt, Op, Mlp);
  flash_combine<<<dim3(4096), 256, 0, stream>>>(Op, Mlp, Ao);

  gemm_bt2<float><<<dim3(32, 16), 512, 0, stream>>>(Ao, owb, out, 2048, 2048, 2048);
}

// Round 16
// 209.919 us; speedup vs baseline: 1.2984x; 1.0119x over previous
//
#include <hip/hip_runtime.h>

// ---------------------------------------------------------------------------
// MLA (LoraQKV) pipeline for MI355X, bf16 MFMA everywhere.
//   1) cvt_all; 2) gemm C1 = hs@W1^T (bf16); 3) rmsnorm_rope;
//   4) grouped gemm Qfb+KVfb (bf16) with V-transpose FUSED into the epilogue
//      of odd-column KV blocks (writes Vt directly; kv_post eliminated);
//   5) flash_attn (Q-RoPE fused, K from KVfb+kr, 2-way key-split, bf16
//      partials) + combine; 6) gemm out = Ao@o_w^T (f32).
// R16: kv_post fused into gemm pair epilogue (LDS transpose of acc ->
//     coalesced Vt write; KVfb V-half never written/read). Vt moved to ws+0
//     (W1b region) to avoid overlaying the pair's B operand. -16MB traffic,
//     -1 launch. All math bit-identical to R15.
// ---------------------------------------------------------------------------

typedef __attribute__((ext_vector_type(8))) __bf16 bf16x8;
typedef __attribute__((ext_vector_type(4))) float f32x4;
typedef __attribute__((ext_vector_type(4))) unsigned u32x4;

__device__ __forceinline__ unsigned short f2bf(float f) {
  unsigned int x = __builtin_bit_cast(unsigned int, f);
  x += 0x7fffu + ((x >> 16) & 1u);
  return (unsigned short)(x >> 16);
}
__device__ __forceinline__ float bf2f(unsigned short u) {
  unsigned int x = ((unsigned int)u) << 16;
  return __builtin_bit_cast(float, x);
}
__device__ __forceinline__ void gload_lds16(const void* g, void* l) {
  __builtin_amdgcn_global_load_lds(
      (const __attribute__((address_space(1))) void*)g,
      (__attribute__((address_space(3))) void*)l, 16, 0, 0);
}
__device__ __forceinline__ void cstore(float* C, size_t i, float v) { C[i] = v; }
__device__ __forceinline__ void cstore(unsigned short* C, size_t i, float v) { C[i] = f2bf(v); }

// ---------------- segmented convert (all f32->bf16 converts in one launch) --
struct CvtSegs {
  const float* src[6];
  unsigned short* dst[6];
  unsigned int n_src[6];
  unsigned int n_tot[6];
  unsigned int blk0[7];
};

__global__ __launch_bounds__(256) void cvt_all(CvtSegs sg) {
  int b = blockIdx.x;
  int seg = 0;
#pragma unroll
  for (int k = 0; k < 5; ++k)
    if (b >= (int)sg.blk0[k + 1]) seg = k + 1;
  size_t i = ((size_t)(b - sg.blk0[seg]) * 256 + threadIdx.x) * 4;
  if (i >= sg.n_tot[seg]) return;
  unsigned short o0 = 0, o1 = 0, o2 = 0, o3 = 0;
  if (i < sg.n_src[seg]) {
    float4 v = *reinterpret_cast<const float4*>(sg.src[seg] + i);
    o0 = f2bf(v.x); o1 = f2bf(v.y); o2 = f2bf(v.z); o3 = f2bf(v.w);
  }
  *reinterpret_cast<ushort4*>(sg.dst[seg] + i) = make_ushort4(o0, o1, o2, o3);
}

// ---------------- GEMM core (shared by single and grouped kernels) ----------
// 128x64 tile, BK=64, 512 threads (8 waves 4x2, wave tile 32x32), dbuf LDS
// (carved from one 48KB block), 2-phase; T2 swizzle via pre-swizzled source.
// VT=true: instead of storing C, transpose the 128x64 tile through LDS and
// write it to VtOut[vh*64 + col][bm + row] (fused V^T epilogue).
template <typename OutT, bool VT>
__device__ __forceinline__ void gemm_body(const unsigned short* __restrict__ A,
                                          const unsigned short* __restrict__ B,
                                          OutT* __restrict__ C,
                                          int N, int K, int bm, int bn,
                                          unsigned short* shm,
                                          unsigned short* VtOut, int vh) {
  unsigned short* lA0 = shm;
  unsigned short* lA1 = shm + 8192;
  unsigned short* lB0 = shm + 16384;
  unsigned short* lB1 = shm + 20480;
  const int tid = threadIdx.x, lane = tid & 63, wv = tid >> 6;
  const int wr = wv >> 1, wc = wv & 1;             // 4x2 wave grid

  f32x4 acc[2][2] = {};

  const int ar0 = tid >> 3;
  const int acol = (((tid & 7) ^ ((tid >> 3) & 7))) * 8;   // T2 pre-swizzled src
  const int swz = lane & 7;

  auto stage = [&](unsigned short* la, unsigned short* lb, int k0) {
#pragma unroll
    for (int i = 0; i < 2; ++i)
      gload_lds16(A + (size_t)(bm + i * 64 + ar0) * K + k0 + acol,
                  &la[(i * 512 + wv * 64) * 8]);
    gload_lds16(B + (size_t)(bn + ar0) * K + k0 + acol, &lb[(wv * 64) * 8]);
  };

  auto compute = [&](const unsigned short* la, const unsigned short* lb) {
#pragma unroll
    for (int ks = 0; ks < 2; ++ks) {
      const int ch = ((ks * 4 + (lane >> 4)) ^ swz) * 8;
      bf16x8 af[2], bfr[2];
#pragma unroll
      for (int m = 0; m < 2; ++m)
        af[m] = *reinterpret_cast<const bf16x8*>(
            &la[(wr * 32 + m * 16 + (lane & 15)) * 64 + ch]);
#pragma unroll
      for (int n = 0; n < 2; ++n)
        bfr[n] = *reinterpret_cast<const bf16x8*>(
            &lb[(wc * 32 + n * 16 + (lane & 15)) * 64 + ch]);
      __builtin_amdgcn_s_setprio(1);
#pragma unroll
      for (int m = 0; m < 2; ++m)
#pragma unroll
        for (int n = 0; n < 2; ++n)
          acc[m][n] = __builtin_amdgcn_mfma_f32_16x16x32_bf16(af[m], bfr[n], acc[m][n], 0, 0, 0);
      __builtin_amdgcn_s_setprio(0);
    }
  };

  stage(lA0, lB0, 0);
  for (int k0 = 0; k0 < K; k0 += 128) {   // K % 128 == 0 for all call sites
    __syncthreads();                      // stage(k0) -> buf0 ready
    stage(lA1, lB1, k0 + 64);             // in flight during compute(buf0)
    compute(lA0, lB0);
    __syncthreads();                      // buf1 ready (hidden); buf0 free
    if (k0 + 128 < K) stage(lA0, lB0, k0 + 128);
    compute(lA1, lB1);
  }

  if constexpr (!VT) {
    const int r0 = bm + wr * 32, c0 = bn + wc * 32;
#pragma unroll
    for (int m = 0; m < 2; ++m)
#pragma unroll
      for (int n = 0; n < 2; ++n)
#pragma unroll
        for (int r = 0; r < 4; ++r)
          cstore(C, (size_t)(r0 + m * 16 + (lane >> 4) * 4 + r) * N + c0 + n * 16 + (lane & 15),
                 acc[m][n][r]);
  } else {
    // fused V^T: acc -> LDS [64 cols][129 pad] -> coalesced Vt rows
    __syncthreads();                      // all waves done with lA/lB reads
    unsigned short* lT = shm;             // 64*129 ushorts = 16.5 KB
#pragma unroll
    for (int m = 0; m < 2; ++m)
#pragma unroll
      for (int n = 0; n < 2; ++n)
#pragma unroll
        for (int r = 0; r < 4; ++r) {
          int rl = wr * 32 + m * 16 + (lane >> 4) * 4 + r;   // 0..127 (s)
          int cl = wc * 32 + n * 16 + (lane & 15);           // 0..63  (d)
          lT[cl * 129 + rl] = f2bf(acc[m][n][r]);
        }
    __syncthreads();
#pragma unroll
    for (int it = 0; it < 2; ++it) {
      int gg = it * 512 + tid;
      int d = gg >> 4, sc = (gg & 15) * 8;
      unsigned short t0 = lT[d * 129 + sc + 0], t1 = lT[d * 129 + sc + 1];
      unsigned short t2 = lT[d * 129 + sc + 2], t3 = lT[d * 129 + sc + 3];
      unsigned short t4 = lT[d * 129 + sc + 4], t5 = lT[d * 129 + sc + 5];
      unsigned short t6 = lT[d * 129 + sc + 6], t7 = lT[d * 129 + sc + 7];
      unsigned short* dst = VtOut + ((size_t)vh * 64 + d) * 2048 + bm + sc;
      *reinterpret_cast<ushort4*>(dst) = make_ushort4(t0, t1, t2, t3);
      *reinterpret_cast<ushort4*>(dst + 4) = make_ushort4(t4, t5, t6, t7);
    }
  }
}

template <typename OutT>
__global__ __launch_bounds__(512, 4) void gemm_bt2(const unsigned short* __restrict__ A,
                                                   const unsigned short* __restrict__ B,
                                                   OutT* __restrict__ C,
                                                   int M, int N, int K) {
  __shared__ unsigned short shm[24576];
  // T1: XCD-aware block swizzle (nwg % 8 == 0 at every call site)
  unsigned nwg = gridDim.x * gridDim.y;
  unsigned lid = blockIdx.y * gridDim.x + blockIdx.x;
  unsigned swz_id = (lid & 7) * (nwg >> 3) + (lid >> 3);
  const int bm = (int)(swz_id / gridDim.x) * 128;
  const int bn = (int)(swz_id % gridDim.x) * 64;
  gemm_body<OutT, false>(A, B, C, N, K, bm, bn, shm, nullptr, 0);
}

// grouped: blocks [0,1024) -> problem 0 (Q, K0), [1024,2048) -> problem 1
// (KV, K1). Both M=2048, N=4096 (16 x 64 tile grid per problem). Problem-1
// blocks on odd column-tiles hold V halves -> fused V^T epilogue to Vt.
__global__ __launch_bounds__(512, 4) void gemm_bt2_pair(const unsigned short* __restrict__ A0,
                                                        const unsigned short* __restrict__ B0,
                                                        unsigned short* __restrict__ C0,
                                                        int K0,
                                                        const unsigned short* __restrict__ A1,
                                                        const unsigned short* __restrict__ B1,
                                                        unsigned short* __restrict__ C1,
                                                        int K1,
                                                        unsigned short* __restrict__ Vt) {
  __shared__ unsigned short shm[24576];
  const int p = blockIdx.x >= 1024;
  unsigned lid = blockIdx.x & 1023;
  unsigned swz_id = (lid & 7) * 128 + (lid >> 3);       // T1 within the half
  const int bm = (int)(swz_id >> 6) * 128;
  const int bn = (int)(swz_id & 63) * 64;
  if (!p) {
    gemm_body<unsigned short, false>(A0, B0, C0, 4096, K0, bm, bn, shm, nullptr, 0);
  } else {
    const int cb = bn >> 6;
    if (cb & 1)   // V half of head cb>>1: write Vt directly, skip KVfb
      gemm_body<unsigned short, true>(A1, B1, C1, 4096, K1, bm, bn, shm, Vt, cb >> 1);
    else
      gemm_body<unsigned short, false>(A1, B1, C1, 4096, K1, bm, bn, shm, nullptr, 0);
  }
}

// ---------------- RMSNorm(q_lat), RMSNorm(c_kv), RoPE(k_rope) ---------------
// C1 is bf16 (stats accumulated in f32).
__global__ __launch_bounds__(256) void rmsnorm_rope(const unsigned short* __restrict__ C1,
                                                    const float* __restrict__ qw,
                                                    const float* __restrict__ kvw,
                                                    const float* __restrict__ cosp,
                                                    const float* __restrict__ sinp,
                                                    unsigned short* __restrict__ qn,
                                                    unsigned short* __restrict__ ckvn,
                                                    unsigned short* __restrict__ kr) {
  const int s = blockIdx.x, tid = threadIdx.x;
  const unsigned short* row = C1 + (size_t)s * 2048;
  __shared__ float red[4];

  ushort4 v4 = *reinterpret_cast<const ushort4*>(row + tid * 4);
  float vx = bf2f(v4.x), vy = bf2f(v4.y), vz = bf2f(v4.z), vw = bf2f(v4.w);
  float ss = vx * vx + vy * vy + vz * vz + vw * vw;
  ss += __shfl_xor(ss, 32); ss += __shfl_xor(ss, 16); ss += __shfl_xor(ss, 8);
  ss += __shfl_xor(ss, 4);  ss += __shfl_xor(ss, 2);  ss += __shfl_xor(ss, 1);
  if ((tid & 63) == 0) red[tid >> 6] = ss;
  __syncthreads();
  float rs = rsqrtf((red[0] + red[1] + red[2] + red[3]) * (1.f / 1024.f) + 1e-6f);
  {
    float4 w = *reinterpret_cast<const float4*>(qw + tid * 4);
    *reinterpret_cast<ushort4*>(qn + (size_t)s * 1024 + tid * 4) =
        make_ushort4(f2bf(vx * rs * w.x), f2bf(vy * rs * w.y),
                     f2bf(vz * rs * w.z), f2bf(vw * rs * w.w));
  }

  float ux = 0.f, uy = 0.f, uz = 0.f, uw = 0.f;
  if (tid < 224) {
    ushort4 u4 = *reinterpret_cast<const ushort4*>(row + 1024 + tid * 4);
    ux = bf2f(u4.x); uy = bf2f(u4.y); uz = bf2f(u4.z); uw = bf2f(u4.w);
  }
  ss = ux * ux + uy * uy + uz * uz + uw * uw;
  ss += __shfl_xor(ss, 32); ss += __shfl_xor(ss, 16); ss += __shfl_xor(ss, 8);
  ss += __shfl_xor(ss, 4);  ss += __shfl_xor(ss, 2);  ss += __shfl_xor(ss, 1);
  __syncthreads();
  if ((tid & 63) == 0) red[tid >> 6] = ss;
  __syncthreads();
  rs = rsqrtf((red[0] + red[1] + red[2] + red[3]) * (1.f / 896.f) + 1e-6f);
  if (tid < 224) {
    float4 w = *reinterpret_cast<const float4*>(kvw + tid * 4);
    *reinterpret_cast<ushort4*>(ckvn + (size_t)s * 896 + tid * 4) =
        make_ushort4(f2bf(ux * rs * w.x), f2bf(uy * rs * w.y),
                     f2bf(uz * rs * w.z), f2bf(uw * rs * w.w));
  }

  if (tid < 64) {
    int d = tid;
    float x = bf2f(row[1920 + d]);
    float part = (d < 32) ? -bf2f(row[1920 + d + 32]) : bf2f(row[1920 + d - 32]);
    float vv = x * cosp[(size_t)s * 64 + d] + part * sinp[(size_t)s * 64 + d];
    kr[(size_t)s * 64 + d] = f2bf(vv);
  }
}

// ---------------- flash attention (causal, 2-way key-split partials) --------
// grid (32 heads, 64): qb = 31-(y>>1) (LPT), j = y&1; tiles t%2==j, t<=qb.
// 4 blocks/CU (VGPR 64, no spill). Q-load fused RoPE+SCALE*log2e; K staged
// straight from KVfb (nope cols) + kr (rope). Partial O bf16; (m,l) f32.
__global__ __launch_bounds__(256, 4) void flash_attn(const unsigned short* __restrict__ Qfb,
                                                     const unsigned short* __restrict__ KVfb,
                                                     const unsigned short* __restrict__ kr,
                                                     const float* __restrict__ cosp,
                                                     const float* __restrict__ sinp,
                                                     const unsigned short* __restrict__ Vt,
                                                     unsigned short* __restrict__ Op,
                                                     float2* __restrict__ Ml) {
  __shared__ unsigned short lK0[64 * 128], lK1[64 * 128];
  const int tid = threadIdx.x, lane = tid & 63, wv = tid >> 6;
  const int h = blockIdx.x;
  const int qb = 31 - ((int)blockIdx.y >> 1);            // LPT: heavy first
  const int j = (int)blockIdx.y & 1;                     // key-split half
  const int q0 = qb * 64;
  const int firstrow = q0 + wv * 16;
  const int g = lane >> 4;
  const int qa = firstrow + (lane & 15);                 // this lane's q-row
  const float SC = 0.18033688f;                          // 0.125 * log2(e)

  // ---- Q load + fused RoPE + scale (once per block) ----
  bf16x8 qf[4];
  {
    const unsigned short* qr = Qfb + (size_t)qa * 4096 + h * 128;
    float raw[4][8];
#pragma unroll
    for (int ks = 0; ks < 4; ++ks) {
      ushort4 u0 = *reinterpret_cast<const ushort4*>(qr + ks * 32 + g * 8);
      ushort4 u1 = *reinterpret_cast<const ushort4*>(qr + ks * 32 + g * 8 + 4);
      raw[ks][0] = bf2f(u0.x); raw[ks][1] = bf2f(u0.y);
      raw[ks][2] = bf2f(u0.z); raw[ks][3] = bf2f(u0.w);
      raw[ks][4] = bf2f(u1.x); raw[ks][5] = bf2f(u1.y);
      raw[ks][6] = bf2f(u1.z); raw[ks][7] = bf2f(u1.w);
    }
    const float* cp = cosp + (size_t)qa * 64 + g * 8;
    const float* sp = sinp + (size_t)qa * 64 + g * 8;
    float c0[8], s0[8], c1[8], s1[8];
    {
      float4 a = *reinterpret_cast<const float4*>(cp);
      float4 b = *reinterpret_cast<const float4*>(cp + 4);
      c0[0]=a.x;c0[1]=a.y;c0[2]=a.z;c0[3]=a.w;c0[4]=b.x;c0[5]=b.y;c0[6]=b.z;c0[7]=b.w;
      a = *reinterpret_cast<const float4*>(cp + 32);
      b = *reinterpret_cast<const float4*>(cp + 36);
      c1[0]=a.x;c1[1]=a.y;c1[2]=a.z;c1[3]=a.w;c1[4]=b.x;c1[5]=b.y;c1[6]=b.z;c1[7]=b.w;
      a = *reinterpret_cast<const float4*>(sp);
      b = *reinterpret_cast<const float4*>(sp + 4);
      s0[0]=a.x;s0[1]=a.y;s0[2]=a.z;s0[3]=a.w;s0[4]=b.x;s0[5]=b.y;s0[6]=b.z;s0[7]=b.w;
      a = *reinterpret_cast<const float4*>(sp + 32);
      b = *reinterpret_cast<const float4*>(sp + 36);
      s1[0]=a.x;s1[1]=a.y;s1[2]=a.z;s1[3]=a.w;s1[4]=b.x;s1[5]=b.y;s1[6]=b.z;s1[7]=b.w;
    }
    alignas(16) unsigned short pk[4][8];
#pragma unroll
    for (int e = 0; e < 8; ++e) {
      pk[0][e] = f2bf(raw[0][e] * SC);
      pk[1][e] = f2bf(raw[1][e] * SC);
      pk[2][e] = f2bf((raw[2][e] * c0[e] - raw[3][e] * s0[e]) * SC);
      pk[3][e] = f2bf((raw[3][e] * c1[e] + raw[2][e] * s1[e]) * SC);
    }
#pragma unroll
    for (int ks = 0; ks < 4; ++ks)
      qf[ks] = *reinterpret_cast<const bf16x8*>(pk[ks]);
  }

  f32x4 o_acc[4] = {};
  float mrow = -1e30f, lrow = 0.f;   // per-lane: stats of q-row qa

  const int sl0 = ((g & 1) * 2) * 16 + (lane & 15);   // src lane, m=0,1
  const int sl1 = sl0 + 16;                           // src lane, m=2,3
  const bool hi = g >= 2;                             // selects src_n = 2ks+1

  const int krow = wv * 4 + (lane >> 4);
  const int cs = (lane & 15) ^ (krow & 7);            // swizzled source chunk
  const int swz = lane & 7;                           // read-side row&7

  auto stage = [&](int t, unsigned short* lK) {
    int jj = t * 64;
#pragma unroll
    for (int i = 0; i < 4; ++i) {
      int s = jj + i * 16 + krow;
      const unsigned short* src =
          (cs < 8) ? KVfb + (size_t)s * 4096 + h * 128 + cs * 8
                   : kr + (size_t)s * 64 + (cs - 8) * 8;
      gload_lds16(src, &lK[(i * 16 + wv * 4) * 128]);
    }
  };

  auto loadV = [&](int j0, bf16x8 (&vr)[2][4]) {
#pragma unroll
    for (int ks = 0; ks < 2; ++ks)
#pragma unroll
      for (int n = 0; n < 4; ++n)
        vr[ks][n] = *reinterpret_cast<const bf16x8*>(
            Vt + ((size_t)h * 64 + n * 16 + (lane & 15)) * 2048 + j0 + ks * 32 +
            (lane >> 4) * 8);
  };

  auto computeT = [&](int j0, const unsigned short* lK, const bf16x8 (&vr)[2][4]) {
    f32x4 sT[4] = {};
    __builtin_amdgcn_s_setprio(1);
#pragma unroll
    for (int n = 0; n < 4; ++n)
#pragma unroll
      for (int ks = 0; ks < 4; ++ks) {
        bf16x8 kf = *reinterpret_cast<const bf16x8*>(
            &lK[(n * 16 + (lane & 15)) * 128 + (((ks * 4 + (lane >> 4)) ^ swz)) * 8]);
        sT[n] = __builtin_amdgcn_mfma_f32_16x16x32_bf16(kf, qf[ks], sT[n], 0, 0, 0);
      }
    __builtin_amdgcn_s_setprio(0);

    if (j0 == q0) {  // diagonal tile: causal mask
#pragma unroll
      for (int n = 0; n < 4; ++n)
#pragma unroll
        for (int r = 0; r < 4; ++r) {
          int key = j0 + n * 16 + g * 4 + r;
          if (key > qa) sT[n][r] = -1e30f;
        }
    }

    // tree max over 16 values + 2 shfl
    float tm[4];
#pragma unroll
    for (int n = 0; n < 4; ++n)
      tm[n] = fmaxf(fmaxf(sT[n][0], sT[n][1]), fmaxf(sT[n][2], sT[n][3]));
    float mx = fmaxf(fmaxf(tm[0], tm[1]), fmaxf(tm[2], tm[3]));
    mx = fmaxf(mx, __shfl_xor(mx, 16));
    mx = fmaxf(mx, __shfl_xor(mx, 32));

    if (__any(mx - mrow > 8.0f)) {   // defer-max (T13), exp2 domain
      float mn = fmaxf(mrow, mx);
      float sf = exp2f(mrow - mn);
      mrow = mn;
      lrow *= sf;
      float sfr[4];
#pragma unroll
      for (int r = 0; r < 4; ++r) sfr[r] = __shfl(sf, (lane >> 4) * 4 + r);
#pragma unroll
      for (int n = 0; n < 4; ++n)
#pragma unroll
        for (int r = 0; r < 4; ++r) o_acc[n][r] *= sfr[r];
    }

    float psn[4];
    unsigned dw[4][2];
#pragma unroll
    for (int n = 0; n < 4; ++n) {
      float p0 = exp2f(sT[n][0] - mrow), p1 = exp2f(sT[n][1] - mrow);
      float p2 = exp2f(sT[n][2] - mrow), p3 = exp2f(sT[n][3] - mrow);
      psn[n] = (p0 + p1) + (p2 + p3);
      asm("v_cvt_pk_bf16_f32 %0, %1, %2" : "=v"(dw[n][0]) : "v"(p0), "v"(p1));
      asm("v_cvt_pk_bf16_f32 %0, %1, %2" : "=v"(dw[n][1]) : "v"(p2), "v"(p3));
    }
    float ps = (psn[0] + psn[1]) + (psn[2] + psn[3]);
    ps += __shfl_xor(ps, 16);
    ps += __shfl_xor(ps, 32);
    lrow += ps;

#pragma unroll
    for (int ks = 0; ks < 2; ++ks) {
      unsigned A0 = __shfl(dw[2 * ks][0], sl0);
      unsigned B0 = __shfl(dw[2 * ks + 1][0], sl0);
      unsigned A1 = __shfl(dw[2 * ks][1], sl0);
      unsigned B1 = __shfl(dw[2 * ks + 1][1], sl0);
      unsigned A2 = __shfl(dw[2 * ks][0], sl1);
      unsigned B2 = __shfl(dw[2 * ks + 1][0], sl1);
      unsigned A3 = __shfl(dw[2 * ks][1], sl1);
      unsigned B3 = __shfl(dw[2 * ks + 1][1], sl1);
      u32x4 mm;
      mm.x = hi ? B0 : A0; mm.y = hi ? B1 : A1;
      mm.z = hi ? B2 : A2; mm.w = hi ? B3 : A3;
      bf16x8 pa = __builtin_bit_cast(bf16x8, mm);
      __builtin_amdgcn_s_setprio(1);
#pragma unroll
      for (int n = 0; n < 4; ++n)
        o_acc[n] = __builtin_amdgcn_mfma_f32_16x16x32_bf16(pa, vr[ks][n], o_acc[n], 0, 0, 0);
      __builtin_amdgcn_s_setprio(0);
    }
  };

  // tiles t = j, j+2, ..., <= qb  (empty for qb=0,j=1: falls through)
  bf16x8 vr[2][4];
  unsigned short* cur = lK0;
  unsigned short* nxt = lK1;
  if (j <= qb) stage(j, cur);
  for (int t = j; t <= qb; t += 2) {
    __syncthreads();                         // cur ready (stage issued 1 compute ago)
    if (t + 2 <= qb) stage(t + 2, nxt);      // lands under computeT(t)
    loadV(t * 64, vr);                       // consumed at PV; hides under QK^T
    computeT(t * 64, cur, vr);
    unsigned short* tmp = cur; cur = nxt; nxt = tmp;
  }

  // partial epilogue: unnormalized O (bf16) + (m,l) per q-row (f32)
  unsigned short* op = Op + (size_t)j * 4194304 + ((size_t)h * 2048 + firstrow) * 64;
#pragma unroll
  for (int n = 0; n < 4; ++n)
#pragma unroll
    for (int r = 0; r < 4; ++r)
      op[(size_t)(g * 4 + r) * 64 + n * 16 + (lane & 15)] = f2bf(o_acc[n][r]);
  if (lane < 16)
    Ml[(size_t)j * 65536 + h * 2048 + qa] = make_float2(mrow, lrow);
}

// ---------------- flash combine: LSE-merge the two partials -----------------
__global__ __launch_bounds__(256) void flash_combine(const unsigned short* __restrict__ Op,
                                                     const float2* __restrict__ Ml,
                                                     unsigned short* __restrict__ Ao) {
  size_t i4 = ((size_t)blockIdx.x * 256 + threadIdx.x) * 4;  // over 2048*2048
  int s = (int)(i4 >> 11);
  int c = (int)(i4 & 2047);
  int h = c >> 6, d = c & 63;
  float2 a = Ml[h * 2048 + s];
  float2 b = Ml[65536 + h * 2048 + s];
  float M = fmaxf(a.x, b.x);
  float w0 = exp2f(a.x - M), w1 = exp2f(b.x - M);
  float inv = 1.f / (w0 * a.y + w1 * b.y);
  size_t pidx = ((size_t)h * 2048 + s) * 64 + d;
  ushort4 p0 = *reinterpret_cast<const ushort4*>(Op + pidx);
  ushort4 p1 = *reinterpret_cast<const ushort4*>(Op + 4194304 + pidx);
  *reinterpret_cast<ushort4*>(Ao + (size_t)s * 2048 + h * 64 + d) =
      make_ushort4(f2bf((w0 * bf2f(p0.x) + w1 * bf2f(p1.x)) * inv),
                   f2bf((w0 * bf2f(p0.y) + w1 * bf2f(p1.y)) * inv),
                   f2bf((w0 * bf2f(p0.z) + w1 * bf2f(p1.z)) * inv),
                   f2bf((w0 * bf2f(p0.w) + w1 * bf2f(p1.w)) * inv));
}

// ---------------------------------------------------------------------------
extern "C" void kernel_launch(void* const* d_in, const int* in_sizes, int n_in,
                              void* d_out, int out_size, void* d_ws, size_t ws_size,
                              hipStream_t stream) {
  const float* hs   = (const float*)d_in[0];
  const float* cosp = (const float*)d_in[1];
  const float* sinp = (const float*)d_in[2];
  const float* qaw  = (const float*)d_in[3];
  const float* qaln = (const float*)d_in[4];
  const float* qbwf = (const float*)d_in[5];
  const float* kvaw = (const float*)d_in[6];
  const float* kvln = (const float*)d_in[7];
  const float* kvbwf= (const float*)d_in[8];
  const float* owf  = (const float*)d_in[9];
  float* out = (float*)d_out;
  char* ws = (char*)d_ws;
  const size_t MB = 1u << 20;

  // overlay map (lifetimes):
  unsigned short* W1b  = (unsigned short*)(ws + 0);        // 8 MB   [dead after gemm1]
  unsigned short* Vt   = (unsigned short*)(ws + 0);        // 8 MB   (pair V^T out; dead after flash)
  unsigned short* Ao   = (unsigned short*)(ws + 0);        // 8 MB   (combine out, after flash)
  unsigned short* qbw  = (unsigned short*)(ws + 8 * MB);   // 8 MB   [dead after gemm2]
  unsigned short* kvbw = (unsigned short*)(ws + 16 * MB);  // 7 MB   [dead after gemm2]
  unsigned short* owb  = (unsigned short*)(ws + 23 * MB);  // 8 MB
  unsigned short* hsb  = (unsigned short*)(ws + 31 * MB);  // 8 MB   [dead after gemm1]
  unsigned short* Qfb  = (unsigned short*)(ws + 31 * MB);  // 16 MB  (pair out, raw Q bf16)
  unsigned short* C1b  = (unsigned short*)(ws + 47 * MB);  // 8 MB   [dead after rmsnorm]
  unsigned short* KVfb = (unsigned short*)(ws + 63 * MB);  // 16 MB  (pair out; V-half unused)
  unsigned short* kr   = (unsigned short*)(ws + 79 * MB);  // 0.25 MB
  unsigned short* qln  = (unsigned short*)(ws + 80 * MB);  // 4 MB   [dead after gemm2]
  unsigned short* ckvn = (unsigned short*)(ws + 84 * MB);  // 3.5 MB [dead after gemm2]
  unsigned short* Op   = (unsigned short*)(ws + 88 * MB);  // 2x8.39 MB (flash partials, bf16)
  float2*         Mlp  = (float2*)(ws + 106 * MB);         // 2x0.5 MB
  (void)ws_size; (void)in_sizes; (void)n_in; (void)out_size;

  // ---- one fused convert launch (6 segments) ----
  CvtSegs sg;
  sg.src[0] = qaw;   sg.dst[0] = W1b;                      sg.n_src[0] = 1024u * 2048u; sg.n_tot[0] = 1024u * 2048u;
  sg.src[1] = kvaw;  sg.dst[1] = W1b + (size_t)1024 * 2048; sg.n_src[1] = 960u * 2048u;  sg.n_tot[1] = 1024u * 2048u;
  sg.src[2] = hs;    sg.dst[2] = hsb;                      sg.n_src[2] = 2048u * 2048u; sg.n_tot[2] = 2048u * 2048u;
  sg.src[3] = qbwf;  sg.dst[3] = qbw;                      sg.n_src[3] = 4096u * 1024u; sg.n_tot[3] = 4096u * 1024u;
  sg.src[4] = kvbwf; sg.dst[4] = kvbw;                     sg.n_src[4] = 4096u * 896u;  sg.n_tot[4] = 4096u * 896u;
  sg.src[5] = owf;   sg.dst[5] = owb;                      sg.n_src[5] = 2048u * 2048u; sg.n_tot[5] = 2048u * 2048u;
  sg.blk0[0] = 0;
  for (int k = 0; k < 6; ++k) sg.blk0[k + 1] = sg.blk0[k] + sg.n_tot[k] / 1024u;
  cvt_all<<<dim3(sg.blk0[6]), 256, 0, stream>>>(sg);

  gemm_bt2<unsigned short><<<dim3(32, 16), 512, 0, stream>>>(hsb, W1b, C1b, 2048, 2048, 2048);
  rmsnorm_rope<<<2048, 256, 0, stream>>>(C1b, qaln, kvln, cosp, sinp, qln, ckvn, kr);

  // grouped: Qfb = qln @ qbw^T and KVfb/Vt = ckvn @ kvbw^T in one launch
  // (odd column-tiles of the KV problem write V^T straight to Vt)
  gemm_bt2_pair<<<dim3(2048), 512, 0, stream>>>(qln, qbw, Qfb, 1024,
                                                ckvn, kvbw, KVfb, 896, Vt);

  flash_attn<<<dim3(32, 64), 256, 0, stream>>>(Qfb, KVfb, kr, cosp, sinp, Vt, Op, Mlp);
  flash_combine<<<dim3(4096), 256, 0, stream>>>(Op, Mlp, Ao);

  gemm_bt2<float><<<dim3(32, 16), 512, 0, stream>>>(Ao, owb, out, 2048, 2048, 2048);
}